// Round 1
// baseline (16486.618 us; speedup 1.0000x reference)
//
#include <hip/hip_runtime.h>
#include <math.h>

// ---------------------------------------------------------------------------
// BMPHead (SOLO-style) forward, fp32 baseline.
// Levels: g in {40,36,24,16,12}; B=4, C=256.
// ---------------------------------------------------------------------------

__device__ __forceinline__ float bsample(const float* __restrict__ pl, int H, int W,
                                         float fy, float fx) {
  int y0 = (int)floorf(fy);
  int y1 = min(y0 + 1, H - 1);
  float wy = fy - (float)y0;
  int x0 = (int)floorf(fx);
  int x1 = min(x0 + 1, W - 1);
  float wx = fx - (float)x0;
  const float* r0 = pl + (size_t)y0 * W;
  const float* r1 = pl + (size_t)y1 * W;
  float top = r0[x0] * (1.f - wx) + r0[x1] * wx;
  float bot = r1[x0] * (1.f - wx) + r1[x1] * wx;
  return top * (1.f - wy) + bot * wy;
}

// Builds (B,258,g,g): ch 0..255 = resize(x, g, g) (optionally a fused double
// resize through a mid resolution), ch 256 = x-ramp, ch 257 = y-ramp.
__global__ void build_input(const float* __restrict__ src, float* __restrict__ dst,
                            int H, int W, int midh, int midw, int g, int useMid) {
  int gg = g * g;
  int total = 4 * 258 * gg;
  int idx = blockIdx.x * blockDim.x + threadIdx.x;
  if (idx >= total) return;
  int j = idx % g;
  int rest = idx / g;
  int i = rest % g;
  rest /= g;
  int c = rest % 258;
  int b = rest / 258;
  float val;
  if (c >= 256) {
    int t = (c == 256) ? j : i;
    val = -1.f + 2.f * (float)t / (float)(g - 1);
  } else {
    const float* pl = src + ((size_t)b * 256 + c) * H * W;
    if (!useMid) {
      float fy = (float)i * (float)(H - 1) / (float)(g - 1);
      float fx = (float)j * (float)(W - 1) / (float)(g - 1);
      val = bsample(pl, H, W, fy, fx);
    } else {
      // outer resize position in mid grid
      float fym = (float)i * (float)(midh - 1) / (float)(g - 1);
      float fxm = (float)j * (float)(midw - 1) / (float)(g - 1);
      int y0 = (int)floorf(fym);
      int y1 = min(y0 + 1, midh - 1);
      float wy = fym - (float)y0;
      int x0 = (int)floorf(fxm);
      int x1 = min(x0 + 1, midw - 1);
      float wx = fxm - (float)x0;
      // mid pixel positions in src grid
      float sy0 = (float)y0 * (float)(H - 1) / (float)(midh - 1);
      float sy1 = (float)y1 * (float)(H - 1) / (float)(midh - 1);
      float sx0 = (float)x0 * (float)(W - 1) / (float)(midw - 1);
      float sx1 = (float)x1 * (float)(W - 1) / (float)(midw - 1);
      float v00 = bsample(pl, H, W, sy0, sx0);
      float v01 = bsample(pl, H, W, sy0, sx1);
      float v10 = bsample(pl, H, W, sy1, sx0);
      float v11 = bsample(pl, H, W, sy1, sx1);
      float top = v00 * (1.f - wx) + v01 * wx;
      float bot = v10 * (1.f - wx) + v11 * wx;
      val = top * (1.f - wy) + bot * wy;
    }
  }
  dst[idx] = val;
}

// Generic conv-as-GEMM. Output tile 64 (cout) x 64 (pixels), 256 threads,
// 4x4 micro-tile per thread. K = Cin*TAPS, im2col gathered during staging.
// TAPS=9 -> 3x3 pad 1; TAPS=1 -> 1x1.
template <int TAPS>
__global__ __launch_bounds__(256) void conv_gemm(
    const float* __restrict__ in, const float* __restrict__ w,
    const float* __restrict__ bias, const float* __restrict__ bias2,
    float* __restrict__ out, int Cin, int cinStride, int Cout, int g, int relu,
    int nhwc) {
  const int gg = g * g;
  const int K = Cin * TAPS;
  const int b = blockIdx.z;
  const int co_tile = blockIdx.y * 64;
  const int p_tile = blockIdx.x * 64;
  const float* __restrict__ inb = in + (size_t)b * cinStride * gg;

  __shared__ float As[32][68];  // [kk][co]
  __shared__ float Bs[32][68];  // [kk][p]

  const int t = threadIdx.x;
  const int tx = t & 15;  // pixel group
  const int ty = t >> 4;  // cout group

  float acc[4][4];
#pragma unroll
  for (int i = 0; i < 4; i++)
#pragma unroll
    for (int j = 0; j < 4; j++) acc[i][j] = 0.f;

  for (int k0 = 0; k0 < K; k0 += 32) {
// Stage A (weights): lanes -> consecutive k (coalesced, 128B/line per co)
#pragma unroll
    for (int i = 0; i < 8; i++) {
      int e = i * 256 + t;
      int kk = e & 31;
      int co = e >> 5;
      int k = k0 + kk;
      int coG = co_tile + co;
      As[kk][co] = (k < K && coG < Cout) ? w[(size_t)coG * K + k] : 0.f;
    }
// Stage B (im2col gather): lanes -> consecutive pixels
#pragma unroll
    for (int i = 0; i < 8; i++) {
      int e = i * 256 + t;
      int pp = e & 63;
      int kk = e >> 6;
      int k = k0 + kk;
      int p = p_tile + pp;
      float v = 0.f;
      if (k < K && p < gg) {
        int ci, dy, dx;
        if (TAPS == 9) {
          ci = k / 9;
          int tap = k - ci * 9;
          int t3 = tap / 3;
          dy = t3 - 1;
          dx = tap - t3 * 3 - 1;
        } else {
          ci = k;
          dy = 0;
          dx = 0;
        }
        int y = p / g;
        int x = p - y * g;
        int yy = y + dy;
        int xx = x + dx;
        if (yy >= 0 && yy < g && xx >= 0 && xx < g)
          v = inb[(size_t)ci * gg + yy * g + xx];
      }
      Bs[kk][pp] = v;
    }
    __syncthreads();
#pragma unroll
    for (int kk = 0; kk < 32; kk++) {
      float4 a4 = *reinterpret_cast<const float4*>(&As[kk][ty * 4]);
      float4 b4 = *reinterpret_cast<const float4*>(&Bs[kk][tx * 4]);
      float av[4] = {a4.x, a4.y, a4.z, a4.w};
      float bv[4] = {b4.x, b4.y, b4.z, b4.w};
#pragma unroll
      for (int i = 0; i < 4; i++)
#pragma unroll
        for (int j = 0; j < 4; j++) acc[i][j] = fmaf(av[i], bv[j], acc[i][j]);
    }
    __syncthreads();
  }

  const int co0 = co_tile + ty * 4;
  const int p0 = p_tile + tx * 4;
#pragma unroll
  for (int i = 0; i < 4; i++) {
    int co = co0 + i;
    if (co >= Cout) break;
    float bb = bias[co] + (bias2 ? bias2[co] : 0.f);
    if (!nhwc) {
      if (p0 < gg) {
        float vv[4];
#pragma unroll
        for (int j = 0; j < 4; j++) {
          float x = acc[i][j] + bb;
          if (relu) x = fmaxf(x, 0.f);
          vv[j] = x;
        }
        float4 v4;
        v4.x = vv[0]; v4.y = vv[1]; v4.z = vv[2]; v4.w = vv[3];
        *reinterpret_cast<float4*>(out + ((size_t)b * Cout + co) * gg + p0) = v4;
      }
    } else {
#pragma unroll
      for (int j = 0; j < 4; j++) {
        int p = p0 + j;
        if (p < gg) {
          float x = acc[i][j] + bb;
          if (relu) x = fmaxf(x, 0.f);
          out[((size_t)b * gg + p) * Cout + co] = x;
        }
      }
    }
  }
}

// cate head: 3x3 conv, Cout=1, + bias + sigmoid. 32 pixels/block, 8 ci-groups.
__global__ __launch_bounds__(256) void cate_head_k(const float* __restrict__ in,
                                                   const float* __restrict__ w,
                                                   const float* __restrict__ bias,
                                                   float* __restrict__ heat, int g,
                                                   int cinStride) {
  int gg = g * g;
  int t = threadIdx.x;
  int pi = t & 31;
  int cw = t >> 5;  // 0..7
  int p = blockIdx.x * 32 + pi;
  int b = p / gg;
  float s = 0.f;
  if (b < 4) {
    int pp = p - b * gg;
    int y = pp / g;
    int x = pp - y * g;
    const float* inb = in + (size_t)b * cinStride * gg;
    for (int ci = cw * 32; ci < cw * 32 + 32; ci++) {
      const float* pl = inb + (size_t)ci * gg;
      const float* wp = w + ci * 9;
#pragma unroll
      for (int tap = 0; tap < 9; tap++) {
        int dy = tap / 3 - 1;
        int dx = tap - (tap / 3) * 3 - 1;
        int yy = y + dy;
        int xx = x + dx;
        if (yy >= 0 && yy < g && xx >= 0 && xx < g) s += pl[yy * g + xx] * wp[tap];
      }
    }
  }
  __shared__ float red[256];
  red[t] = s;
  __syncthreads();
  if (cw == 0 && b < 4) {
    float tot = bias[0];
#pragma unroll
    for (int k = 0; k < 8; k++) tot += red[k * 32 + pi];
    heat[p] = 1.f / (1.f + expf(-tot));
  }
}

// points_nms (2x2 max window, pad 1, slice) * heat, written NHWC (C=1).
__global__ void nms_k(const float* __restrict__ heat, float* __restrict__ out, int g) {
  int gg = g * g;
  int idx = blockIdx.x * blockDim.x + threadIdx.x;
  if (idx >= 4 * gg) return;
  int b = idx / gg;
  int pp = idx - b * gg;
  int y = pp / g;
  int x = pp - y * g;
  const float* hb = heat + (size_t)b * gg;
  float c = hb[pp];
  float m = c;
  if (y > 0) {
    m = fmaxf(m, hb[pp - g]);
    if (x > 0) m = fmaxf(m, hb[pp - g - 1]);
  }
  if (x > 0) m = fmaxf(m, hb[pp - 1]);
  out[idx] = (m == c) ? c : 0.f;
}

extern "C" void kernel_launch(void* const* d_in, const int* in_sizes, int n_in,
                              void* d_out, int out_size, void* d_ws, size_t ws_size,
                              hipStream_t stream) {
  const float* feat[5];
  for (int i = 0; i < 5; i++) feat[i] = (const float*)d_in[i];
  const float* smpl_w0 = (const float*)d_in[5];
  const float* smpl_b0 = (const float*)d_in[6];
  const float* smpl_w = (const float*)d_in[7];
  const float* smpl_b = (const float*)d_in[8];
  const float* cate_w0 = (const float*)d_in[9];
  const float* cate_b0 = (const float*)d_in[10];
  const float* cate_w = (const float*)d_in[11];
  const float* cate_b = (const float*)d_in[12];
  const float* cate_head_w = (const float*)d_in[13];
  const float* cate_head_b = (const float*)d_in[14];
  const float* smpl_head_w = (const float*)d_in[15];
  const float* smpl_head_b = (const float*)d_in[16];
  const float* smpl_init = (const float*)d_in[17];
  float* out = (float*)d_out;

  static const int GRIDS[5] = {40, 36, 24, 16, 12};
  static const int SRC_H[5] = {200, 100, 50, 25, 13};
  static const int MID[5] = {100, 0, 0, 0, 25};

  // output offsets
  size_t smpl_off[5], cate_off[5];
  size_t off = 0;
  for (int l = 0; l < 5; l++) {
    smpl_off[l] = off;
    off += (size_t)4 * GRIDS[l] * GRIDS[l] * 157;
  }
  for (int l = 0; l < 5; l++) {
    cate_off[l] = off;
    off += (size_t)4 * GRIDS[l] * GRIDS[l];
  }

  // workspace layout (floats)
  float* bufA = (float*)d_ws;                  // 4*258*1600
  float* bufB = bufA + (size_t)4 * 258 * 1600; // 4*256*1600
  float* bufC = bufB + (size_t)4 * 256 * 1600; // 4*256*1600
  float* heat = bufC + (size_t)4 * 256 * 1600; // 4*1600

  const int LSTRIDE = 256 * 256 * 9;  // per-layer weight stride for smpl_w/cate_w

  for (int l = 0; l < 5; l++) {
    int g = GRIDS[l];
    int gg = g * g;
    int H = SRC_H[l], W = SRC_H[l];
    int mid = MID[l];
    int useMid = mid ? 1 : 0;

    {
      int total = 4 * 258 * gg;
      int blocks = (total + 255) / 256;
      hipLaunchKernelGGL(build_input, dim3(blocks), dim3(256), 0, stream, feat[l],
                         bufA, H, W, mid ? mid : H, mid ? mid : W, g, useMid);
    }

    dim3 cgrid((gg + 63) / 64, 4, 4);  // Cout=256 -> 4 co tiles
    // ---- smpl tower ----
    hipLaunchKernelGGL(conv_gemm<9>, cgrid, dim3(256), 0, stream, bufA, smpl_w0,
                       smpl_b0, (const float*)nullptr, bufB, 258, 258, 256, g, 1, 0);
    hipLaunchKernelGGL(conv_gemm<9>, cgrid, dim3(256), 0, stream, bufB,
                       smpl_w + (size_t)0 * LSTRIDE, smpl_b + 0,
                       (const float*)nullptr, bufC, 256, 256, 256, g, 1, 0);
    hipLaunchKernelGGL(conv_gemm<9>, cgrid, dim3(256), 0, stream, bufC,
                       smpl_w + (size_t)1 * LSTRIDE, smpl_b + 256,
                       (const float*)nullptr, bufB, 256, 256, 256, g, 1, 0);
    hipLaunchKernelGGL(conv_gemm<9>, cgrid, dim3(256), 0, stream, bufB,
                       smpl_w + (size_t)2 * LSTRIDE, smpl_b + 512,
                       (const float*)nullptr, bufC, 256, 256, 256, g, 1, 0);
    // smpl head: 1x1, Cout=157, +smpl_init, NHWC out
    {
      dim3 hgrid((gg + 63) / 64, 3, 4);
      hipLaunchKernelGGL(conv_gemm<1>, hgrid, dim3(256), 0, stream, bufC,
                         smpl_head_w, smpl_head_b, smpl_init, out + smpl_off[l], 256,
                         256, 157, g, 0, 1);
    }
    // ---- cate tower (reads first 256 channels of bufA) ----
    hipLaunchKernelGGL(conv_gemm<9>, cgrid, dim3(256), 0, stream, bufA, cate_w0,
                       cate_b0, (const float*)nullptr, bufB, 256, 258, 256, g, 1, 0);
    hipLaunchKernelGGL(conv_gemm<9>, cgrid, dim3(256), 0, stream, bufB,
                       cate_w + (size_t)0 * LSTRIDE, cate_b + 0,
                       (const float*)nullptr, bufC, 256, 256, 256, g, 1, 0);
    hipLaunchKernelGGL(conv_gemm<9>, cgrid, dim3(256), 0, stream, bufC,
                       cate_w + (size_t)1 * LSTRIDE, cate_b + 256,
                       (const float*)nullptr, bufB, 256, 256, 256, g, 1, 0);
    hipLaunchKernelGGL(conv_gemm<9>, cgrid, dim3(256), 0, stream, bufB,
                       cate_w + (size_t)2 * LSTRIDE, cate_b + 512,
                       (const float*)nullptr, bufC, 256, 256, 256, g, 1, 0);
    // cate head + sigmoid
    {
      int blocks = (4 * gg + 31) / 32;
      hipLaunchKernelGGL(cate_head_k, dim3(blocks), dim3(256), 0, stream, bufC,
                         cate_head_w, cate_head_b, heat, g, 256);
    }
    // points_nms + NHWC write
    {
      int blocks = (4 * gg + 255) / 256;
      hipLaunchKernelGGL(nms_k, dim3(blocks), dim3(256), 0, stream, heat,
                         out + cate_off[l], g);
    }
  }
  (void)in_sizes; (void)n_in; (void)out_size; (void)ws_size;
}

// Round 2
// 3682.428 us; speedup vs baseline: 4.4771x; 4.4771x over previous
//
#include <hip/hip_runtime.h>
#include <math.h>

// ---------------------------------------------------------------------------
// BMPHead forward, fp32, level-batched.
// Activations stored [c][P] per level, P = 4*g*g (batch folded into pixels).
// One conv launch per tower-stage covers all 5 levels.
// ---------------------------------------------------------------------------

#define NLEV 5

struct LevDesc {
  int tileStart[NLEV + 1];  // cumulative pixel-tiles (64 px each)
  int P[NLEV];
  int g[NLEV];
  int inOff[NLEV];   // float offset into inBase
  int outOff[NLEV];  // float offset into outBase
};

struct BuildDesc {
  const float* src[NLEV];
  int H[NLEV];
  int mid[NLEV];  // 0 = single resize, else fused double-resize via mid
  int P[NLEV];
  int g[NLEV];
  int aOff[NLEV];
};

__device__ __forceinline__ float bsample(const float* __restrict__ pl, int H, int W,
                                         float fy, float fx) {
  int y0 = (int)floorf(fy);
  int y1 = min(y0 + 1, H - 1);
  float wy = fy - (float)y0;
  int x0 = (int)floorf(fx);
  int x1 = min(x0 + 1, W - 1);
  float wx = fx - (float)x0;
  const float* r0 = pl + (size_t)y0 * W;
  const float* r1 = pl + (size_t)y1 * W;
  float top = r0[x0] * (1.f - wx) + r0[x1] * wx;
  float bot = r1[x0] * (1.f - wx) + r1[x1] * wx;
  return top * (1.f - wy) + bot * wy;
}

// Builds [258][P] per level: ch 0..255 = resize(x,g,g), 256 = x-ramp, 257 = y-ramp.
__global__ __launch_bounds__(256) void build_all(BuildDesc bd, float* __restrict__ dst) {
  int l = blockIdx.y;
  int P = bd.P[l];
  int g = bd.g[l];
  int total = 258 * P;
  int idx = blockIdx.x * 256 + threadIdx.x;
  if (idx >= total) return;
  int c = idx / P;
  int p = idx - c * P;
  int gg = g * g;
  int b = p / gg;
  int pr = p - b * gg;
  int i = pr / g;
  int j = pr - i * g;
  float val;
  if (c >= 256) {
    int tt = (c == 256) ? j : i;
    val = -1.f + 2.f * (float)tt / (float)(g - 1);
  } else {
    int H = bd.H[l], W = bd.H[l];
    int mid = bd.mid[l];
    const float* pl = bd.src[l] + ((size_t)b * 256 + c) * H * W;
    if (!mid) {
      float fy = (float)i * (float)(H - 1) / (float)(g - 1);
      float fx = (float)j * (float)(W - 1) / (float)(g - 1);
      val = bsample(pl, H, W, fy, fx);
    } else {
      int midh = mid, midw = mid;
      float fym = (float)i * (float)(midh - 1) / (float)(g - 1);
      float fxm = (float)j * (float)(midw - 1) / (float)(g - 1);
      int y0 = (int)floorf(fym);
      int y1 = min(y0 + 1, midh - 1);
      float wy = fym - (float)y0;
      int x0 = (int)floorf(fxm);
      int x1 = min(x0 + 1, midw - 1);
      float wx = fxm - (float)x0;
      float sy0 = (float)y0 * (float)(H - 1) / (float)(midh - 1);
      float sy1 = (float)y1 * (float)(H - 1) / (float)(midh - 1);
      float sx0 = (float)x0 * (float)(W - 1) / (float)(midw - 1);
      float sx1 = (float)x1 * (float)(W - 1) / (float)(midw - 1);
      float v00 = bsample(pl, H, W, sy0, sx0);
      float v01 = bsample(pl, H, W, sy0, sx1);
      float v10 = bsample(pl, H, W, sy1, sx0);
      float v11 = bsample(pl, H, W, sy1, sx1);
      float top = v00 * (1.f - wx) + v01 * wx;
      float bot = v10 * (1.f - wx) + v11 * wx;
      val = top * (1.f - wy) + bot * wy;
    }
  }
  dst[bd.aOff[l] + idx] = val;
}

// Conv-as-GEMM, all levels in one launch. 64(co) x 64(px) tile, 256 threads,
// 4x4 micro-tile. TAPS=9 -> 3x3 pad 1; TAPS=1 -> 1x1.
template <int TAPS>
__global__ __launch_bounds__(256) void conv_gemm(
    const float* __restrict__ inBase, const float* __restrict__ w,
    const float* __restrict__ bias, const float* __restrict__ bias2,
    float* __restrict__ outBase, LevDesc d, int Cin, int Cout, int relu, int nhwc) {
  int bx = blockIdx.x;
  int l = 0;
#pragma unroll
  for (int i = 1; i < NLEV; i++)
    if (bx >= d.tileStart[i]) l = i;
  const int P = d.P[l];
  const int g = d.g[l];
  const int gg = g * g;
  const int p_tile = (bx - d.tileStart[l]) * 64;
  const int K = Cin * TAPS;
  const int co_tile = blockIdx.y * 64;
  const float* __restrict__ in = inBase + d.inOff[l];
  float* __restrict__ out = outBase + d.outOff[l];

  __shared__ float As[32][68];  // [kk][co]
  __shared__ float Bs[32][68];  // [kk][px]

  const int t = threadIdx.x;
  const int tx = t & 15;
  const int ty = t >> 4;

  // per-thread fixed pixel for B staging
  const int pp = t & 63;
  const int p = p_tile + pp;
  int y, x;
  unsigned vmask = 0;
  {
    int pr = p % gg;
    y = pr / g;
    x = pr - y * g;
    if (TAPS == 9) {
#pragma unroll
      for (int tap = 0; tap < 9; tap++) {
        int dy = tap / 3 - 1, dx = tap % 3 - 1;
        if ((unsigned)(y + dy) < (unsigned)g && (unsigned)(x + dx) < (unsigned)g)
          vmask |= 1u << tap;
      }
    }
  }
  const int pbase = p - g - 1;  // tap(0,0) address offset

  float acc[4][4];
#pragma unroll
  for (int i = 0; i < 4; i++)
#pragma unroll
    for (int j = 0; j < 4; j++) acc[i][j] = 0.f;

  const int akk = t & 31;
  const int aco = t >> 5;

  for (int k0 = 0; k0 < K; k0 += 32) {
    // stage A: lanes -> consecutive k (coalesced)
    {
      int k = k0 + akk;
      bool kok = (k < K);
#pragma unroll
      for (int i = 0; i < 8; i++) {
        int co = i * 8 + aco;
        int coG = co_tile + co;
        As[akk][co] = (kok && coG < Cout) ? w[(size_t)coG * K + k] : 0.f;
      }
    }
    // stage B: lanes -> consecutive pixels (coalesced)
#pragma unroll
    for (int i = 0; i < 8; i++) {
      int kk = i * 4 + (t >> 6);
      int k = k0 + kk;
      float v = 0.f;
      if (TAPS == 9) {
        int ci = k / 9;
        int tap = k - ci * 9;
        int d3 = tap / 3;
        int dxr = tap - d3 * 3;
        if (k < K && ((vmask >> tap) & 1u))
          v = in[(size_t)ci * P + pbase + d3 * g + dxr];
      } else {
        if (k < K) v = in[(size_t)k * P + p];
      }
      Bs[kk][pp] = v;
    }
    __syncthreads();
#pragma unroll
    for (int kk = 0; kk < 32; kk++) {
      float4 a4 = *reinterpret_cast<const float4*>(&As[kk][ty * 4]);
      float4 b4 = *reinterpret_cast<const float4*>(&Bs[kk][tx * 4]);
      float av[4] = {a4.x, a4.y, a4.z, a4.w};
      float bv[4] = {b4.x, b4.y, b4.z, b4.w};
#pragma unroll
      for (int i = 0; i < 4; i++)
#pragma unroll
        for (int j = 0; j < 4; j++) acc[i][j] = fmaf(av[i], bv[j], acc[i][j]);
    }
    __syncthreads();
  }

  const int co0 = co_tile + ty * 4;
  const int p0 = p_tile + tx * 4;
#pragma unroll
  for (int i = 0; i < 4; i++) {
    int co = co0 + i;
    if (co >= Cout) break;
    float bb = bias[co] + (bias2 ? bias2[co] : 0.f);
    if (!nhwc) {
      float vv[4];
#pragma unroll
      for (int j = 0; j < 4; j++) {
        float v2 = acc[i][j] + bb;
        if (relu) v2 = fmaxf(v2, 0.f);
        vv[j] = v2;
      }
      float4 v4;
      v4.x = vv[0]; v4.y = vv[1]; v4.z = vv[2]; v4.w = vv[3];
      *reinterpret_cast<float4*>(out + (size_t)co * P + p0) = v4;
    } else {
#pragma unroll
      for (int j = 0; j < 4; j++) {
        float v2 = acc[i][j] + bb;
        if (relu) v2 = fmaxf(v2, 0.f);
        out[(size_t)(p0 + j) * Cout + co] = v2;
      }
    }
  }
}

// cate head: 3x3 conv Cout=1 + sigmoid, all levels. 32 px/block-row, 8 ci-groups.
__global__ __launch_bounds__(256) void cate_head_all(
    const float* __restrict__ inBase, const float* __restrict__ w,
    const float* __restrict__ bias, float* __restrict__ heat, LevDesc d) {
  int l = blockIdx.y;
  int P = d.P[l], g = d.g[l];
  int gg = g * g;
  int t = threadIdx.x;
  int pi = t & 31, cw = t >> 5;
  int p = blockIdx.x * 32 + pi;
  bool ok = p < P;
  float s = 0.f;
  if (ok) {
    int pr = p % gg;
    int y = pr / g;
    int x = pr - y * g;
    const float* in = inBase + d.inOff[l];
    for (int ci = cw * 32; ci < cw * 32 + 32; ci++) {
      const float* pl = in + (size_t)ci * P + p;
      const float* wp = w + ci * 9;
#pragma unroll
      for (int tap = 0; tap < 9; tap++) {
        int dy = tap / 3 - 1;
        int dx = tap % 3 - 1;
        int yy = y + dy, xx = x + dx;
        if (yy >= 0 && yy < g && xx >= 0 && xx < g) s += pl[dy * g + dx] * wp[tap];
      }
    }
  }
  __shared__ float red[256];
  red[t] = s;
  __syncthreads();
  if (cw == 0 && ok) {
    float tot = bias[0];
#pragma unroll
    for (int k2 = 0; k2 < 8; k2++) tot += red[k2 * 32 + pi];
    heat[d.outOff[l] + p] = 1.f / (1.f + expf(-tot));
  }
}

// points_nms * heat, all levels, NHWC (C=1) write.
__global__ void nms_all(const float* __restrict__ heat, float* __restrict__ out,
                        LevDesc d) {
  int l = blockIdx.y;
  int P = d.P[l], g = d.g[l];
  int gg = g * g;
  int p = blockIdx.x * 256 + threadIdx.x;
  if (p >= P) return;
  int pr = p % gg;
  int y = pr / g;
  int x = pr - y * g;
  const float* hb = heat + d.inOff[l];
  float c = hb[p], m = c;
  if (y > 0) {
    m = fmaxf(m, hb[p - g]);
    if (x > 0) m = fmaxf(m, hb[p - g - 1]);
  }
  if (x > 0) m = fmaxf(m, hb[p - 1]);
  out[d.outOff[l] + p] = (m == c) ? c : 0.f;
}

extern "C" void kernel_launch(void* const* d_in, const int* in_sizes, int n_in,
                              void* d_out, int out_size, void* d_ws, size_t ws_size,
                              hipStream_t stream) {
  const float* feat[5];
  for (int i = 0; i < 5; i++) feat[i] = (const float*)d_in[i];
  const float* smpl_w0 = (const float*)d_in[5];
  const float* smpl_b0 = (const float*)d_in[6];
  const float* smpl_w = (const float*)d_in[7];
  const float* smpl_b = (const float*)d_in[8];
  const float* cate_w0 = (const float*)d_in[9];
  const float* cate_b0 = (const float*)d_in[10];
  const float* cate_w = (const float*)d_in[11];
  const float* cate_b = (const float*)d_in[12];
  const float* cate_head_w = (const float*)d_in[13];
  const float* cate_head_b = (const float*)d_in[14];
  const float* smpl_head_w = (const float*)d_in[15];
  const float* smpl_head_b = (const float*)d_in[16];
  const float* smpl_init = (const float*)d_in[17];
  float* out = (float*)d_out;

  static const int GR[5] = {40, 36, 24, 16, 12};
  static const int SH[5] = {200, 100, 50, 25, 13};
  static const int MIDW[5] = {100, 0, 0, 0, 25};

  int P[5], cumP[6], tS[6];
  cumP[0] = 0;
  tS[0] = 0;
  for (int l = 0; l < 5; l++) {
    P[l] = 4 * GR[l] * GR[l];
    cumP[l + 1] = cumP[l] + P[l];
    tS[l + 1] = tS[l] + P[l] / 64;  // all P divisible by 64
  }
  const int PT = cumP[5];  // 15488

  // output offsets (floats)
  int smpl_off[5], cate_off[5];
  {
    int off = 0;
    for (int l = 0; l < 5; l++) { smpl_off[l] = off; off += P[l] * 157; }
    for (int l = 0; l < 5; l++) { cate_off[l] = off; off += P[l]; }
  }

  // workspace: bufA [258][P], bufB/bufC [256][P], heat [P]  (~47.8 MB)
  float* bufA = (float*)d_ws;
  float* bufB = bufA + (size_t)258 * PT;
  float* bufC = bufB + (size_t)256 * PT;
  float* heat = bufC + (size_t)256 * PT;

  // descriptors
  LevDesc dA, dBC, dHead, dCH, dNms;
  BuildDesc bd;
  for (int l = 0; l < 5; l++) {
    dA.P[l] = dBC.P[l] = dHead.P[l] = dCH.P[l] = dNms.P[l] = P[l];
    dA.g[l] = dBC.g[l] = dHead.g[l] = dCH.g[l] = dNms.g[l] = GR[l];
    dA.inOff[l] = 258 * cumP[l];
    dA.outOff[l] = 256 * cumP[l];
    dBC.inOff[l] = dBC.outOff[l] = 256 * cumP[l];
    dHead.inOff[l] = 256 * cumP[l];
    dHead.outOff[l] = smpl_off[l];
    dCH.inOff[l] = 256 * cumP[l];
    dCH.outOff[l] = cumP[l];
    dNms.inOff[l] = cumP[l];
    dNms.outOff[l] = cate_off[l];
    bd.src[l] = feat[l];
    bd.H[l] = SH[l];
    bd.mid[l] = MIDW[l];
    bd.P[l] = P[l];
    bd.g[l] = GR[l];
    bd.aOff[l] = 258 * cumP[l];
  }
  for (int i = 0; i <= 5; i++) {
    dA.tileStart[i] = dBC.tileStart[i] = dHead.tileStart[i] = tS[i];
    dCH.tileStart[i] = dNms.tileStart[i] = tS[i];
  }

  const int LSTR = 256 * 256 * 9;
  const int NT = tS[5];  // 242 pixel tiles

  // build all level inputs
  {
    int bx = (258 * P[0] + 255) / 256;  // largest level
    hipLaunchKernelGGL(build_all, dim3(bx, 5), dim3(256), 0, stream, bd, bufA);
  }

  dim3 cg(NT, 4);
  // ---- smpl tower ----
  hipLaunchKernelGGL(conv_gemm<9>, cg, dim3(256), 0, stream, bufA, smpl_w0, smpl_b0,
                     (const float*)nullptr, bufB, dA, 258, 256, 1, 0);
  hipLaunchKernelGGL(conv_gemm<9>, cg, dim3(256), 0, stream, bufB,
                     smpl_w + (size_t)0 * LSTR, smpl_b + 0, (const float*)nullptr,
                     bufC, dBC, 256, 256, 1, 0);
  hipLaunchKernelGGL(conv_gemm<9>, cg, dim3(256), 0, stream, bufC,
                     smpl_w + (size_t)1 * LSTR, smpl_b + 256, (const float*)nullptr,
                     bufB, dBC, 256, 256, 1, 0);
  hipLaunchKernelGGL(conv_gemm<9>, cg, dim3(256), 0, stream, bufB,
                     smpl_w + (size_t)2 * LSTR, smpl_b + 512, (const float*)nullptr,
                     bufC, dBC, 256, 256, 1, 0);
  hipLaunchKernelGGL(conv_gemm<1>, dim3(NT, 3), dim3(256), 0, stream, bufC,
                     smpl_head_w, smpl_head_b, smpl_init, out, dHead, 256, 157, 0, 1);
  // ---- cate tower ----
  hipLaunchKernelGGL(conv_gemm<9>, cg, dim3(256), 0, stream, bufA, cate_w0, cate_b0,
                     (const float*)nullptr, bufB, dA, 256, 256, 1, 0);
  hipLaunchKernelGGL(conv_gemm<9>, cg, dim3(256), 0, stream, bufB,
                     cate_w + (size_t)0 * LSTR, cate_b + 0, (const float*)nullptr,
                     bufC, dBC, 256, 256, 1, 0);
  hipLaunchKernelGGL(conv_gemm<9>, cg, dim3(256), 0, stream, bufC,
                     cate_w + (size_t)1 * LSTR, cate_b + 256, (const float*)nullptr,
                     bufB, dBC, 256, 256, 1, 0);
  hipLaunchKernelGGL(conv_gemm<9>, cg, dim3(256), 0, stream, bufB,
                     cate_w + (size_t)2 * LSTR, cate_b + 512, (const float*)nullptr,
                     bufC, dBC, 256, 256, 1, 0);
  {
    int bx = (P[0] + 31) / 32;
    hipLaunchKernelGGL(cate_head_all, dim3(bx, 5), dim3(256), 0, stream, bufC,
                       cate_head_w, cate_head_b, heat, dCH);
  }
  {
    int bx = (P[0] + 255) / 256;
    hipLaunchKernelGGL(nms_all, dim3(bx, 5), dim3(256), 0, stream, heat, out, dNms);
  }
  (void)in_sizes; (void)n_in; (void)out_size; (void)ws_size;
}

// Round 3
// 1220.986 us; speedup vs baseline: 13.5027x; 3.0159x over previous
//
#include <hip/hip_runtime.h>
#include <math.h>
#include <stdint.h>

#define NLEV 5
#define PPT 17616  // sum over levels of 4*(g+2)^2

typedef __attribute__((ext_vector_type(8))) __bf16 bf16x8;
typedef __attribute__((ext_vector_type(4))) float f32x4;
typedef unsigned int u32;
typedef unsigned short u16;

__device__ __forceinline__ u32 f2bf(float f) {
  u32 u = __builtin_bit_cast(u32, f);
  return (u + 0x7FFFu + ((u >> 16) & 1u)) >> 16;
}
__device__ __forceinline__ u32 packSplit(float v) {
  u32 hi = f2bf(v);
  float fhi = __builtin_bit_cast(float, hi << 16);
  u32 lo = f2bf(v - fhi);
  return hi | (lo << 16);
}
__device__ __forceinline__ float unpackSum(u32 w) {
  return __builtin_bit_cast(float, w << 16) +
         __builtin_bit_cast(float, w & 0xFFFF0000u);
}

// ---------------------------------------------------------------------------
// Weight prep: fp32 [Cout][Cin][3][3] -> MFMA A-frag layout, hi/lo bf16 planes.
// elem offset = ((((coT*KS + ks)*2 + f)*2 + wco)*64 + lane)*8 + j
// where ks = tap*CB + cb; co = coT*64+wco*32+f*16+(lane&15); ci = cb*32+(lane>>4)*8+j
// ---------------------------------------------------------------------------
struct PrepDesc {
  const float* src[8];
  int Cin[8];
  int CB[8];
  int dstOff[8];
};

__global__ __launch_bounds__(256) void prep_weights(PrepDesc pd, u16* __restrict__ wHi,
                                                    u16* __restrict__ wLo) {
  int cfg = blockIdx.y;
  int CB = pd.CB[cfg];
  int KS = CB * 9;
  int total = KS * 8192;
  int didx = blockIdx.x * 256 + threadIdx.x;
  if (didx >= total) return;
  int j = didx & 7;
  int lane = (didx >> 3) & 63;
  int wco = (didx >> 9) & 1;
  int f = (didx >> 10) & 1;
  int rest = didx >> 11;
  int ks = rest % KS;
  int coT = rest / KS;
  int tap = ks / CB;
  int cb = ks - tap * CB;
  int ci = cb * 32 + ((lane >> 4) << 3) + j;
  int co = coT * 64 + wco * 32 + f * 16 + (lane & 15);
  int Cin = pd.Cin[cfg];
  float v = 0.f;
  if (ci < Cin) v = pd.src[cfg][((size_t)co * Cin + ci) * 9 + tap];
  u32 hi = f2bf(v);
  float fhi = __builtin_bit_cast(float, hi << 16);
  u32 lo = f2bf(v - fhi);
  wHi[pd.dstOff[cfg] + didx] = (u16)hi;
  wLo[pd.dstOff[cfg] + didx] = (u16)lo;
}

// ---------------------------------------------------------------------------
// build: resize (optionally fused double resize) + coord ramps -> halo u32 acts
// ---------------------------------------------------------------------------
struct BuildDesc {
  const float* src[NLEV];
  int H[NLEV];
  int mid[NLEV];
  int P[NLEV];
  int g[NLEV];
  int padOff[NLEV];
};

__device__ __forceinline__ float bsample(const float* __restrict__ pl, int H, int W,
                                         float fy, float fx) {
  int y0 = (int)floorf(fy);
  int y1 = min(y0 + 1, H - 1);
  float wy = fy - (float)y0;
  int x0 = (int)floorf(fx);
  int x1 = min(x0 + 1, W - 1);
  float wx = fx - (float)x0;
  const float* r0 = pl + (size_t)y0 * W;
  const float* r1 = pl + (size_t)y1 * W;
  float top = r0[x0] * (1.f - wx) + r0[x1] * wx;
  float bot = r1[x0] * (1.f - wx) + r1[x1] * wx;
  return top * (1.f - wy) + bot * wy;
}

__global__ __launch_bounds__(256) void build_all(BuildDesc bd, u32* __restrict__ dst) {
  int l = blockIdx.y;
  int P = bd.P[l];
  int g = bd.g[l];
  int total = 258 * P;
  int idx = blockIdx.x * 256 + threadIdx.x;
  if (idx >= total) return;
  int c = idx / P;
  int p = idx - c * P;
  int gg = g * g;
  int b = p / gg;
  int pr = p - b * gg;
  int i = pr / g;
  int j = pr - i * g;
  float val;
  if (c >= 256) {
    int tt = (c == 256) ? j : i;
    val = -1.f + 2.f * (float)tt / (float)(g - 1);
  } else {
    int H = bd.H[l], W = bd.H[l];
    int mid = bd.mid[l];
    const float* pl = bd.src[l] + ((size_t)b * 256 + c) * H * W;
    if (!mid) {
      float fy = (float)i * (float)(H - 1) / (float)(g - 1);
      float fx = (float)j * (float)(W - 1) / (float)(g - 1);
      val = bsample(pl, H, W, fy, fx);
    } else {
      int midh = mid, midw = mid;
      float fym = (float)i * (float)(midh - 1) / (float)(g - 1);
      float fxm = (float)j * (float)(midw - 1) / (float)(g - 1);
      int y0 = (int)floorf(fym);
      int y1 = min(y0 + 1, midh - 1);
      float wy = fym - (float)y0;
      int x0 = (int)floorf(fxm);
      int x1 = min(x0 + 1, midw - 1);
      float wx = fxm - (float)x0;
      float sy0 = (float)y0 * (float)(H - 1) / (float)(midh - 1);
      float sy1 = (float)y1 * (float)(H - 1) / (float)(midh - 1);
      float sx0 = (float)x0 * (float)(W - 1) / (float)(midw - 1);
      float sx1 = (float)x1 * (float)(W - 1) / (float)(midw - 1);
      float v00 = bsample(pl, H, W, sy0, sx0);
      float v01 = bsample(pl, H, W, sy0, sx1);
      float v10 = bsample(pl, H, W, sy1, sx0);
      float v11 = bsample(pl, H, W, sy1, sx1);
      float top = v00 * (1.f - wx) + v01 * wx;
      float bot = v10 * (1.f - wx) + v11 * wx;
      val = top * (1.f - wy) + bot * wy;
    }
  }
  int gp2 = g + 2;
  dst[(size_t)c * PPT + bd.padOff[l] + b * gp2 * gp2 + (i + 1) * gp2 + (j + 1)] =
      packSplit(val);
}

// ---------------------------------------------------------------------------
// MFMA conv 3x3: 64co x 64px tile, 4 waves (2co x 2p), split-bf16 (3 MFMA).
// ---------------------------------------------------------------------------
struct ConvDesc {
  int tileStart[NLEV + 1];
  int padOff[NLEV];
  int g[NLEV];
};

template <bool MASK>
__global__ __launch_bounds__(256) void conv_mfma(
    const u32* __restrict__ actIn, const u16* __restrict__ wHi,
    const u16* __restrict__ wLo, const float* __restrict__ bias,
    u32* __restrict__ actOut, ConvDesc d, int CB, int CinBuf) {
  int bx = blockIdx.x;
  int l = 0;
#pragma unroll
  for (int i = 1; i < NLEV; i++)
    if (bx >= d.tileStart[i]) l = i;
  const int g = d.g[l];
  const int gp2 = g + 2;
  const int hp2 = gp2 * gp2;
  const int gg = g * g;
  const int padOff = d.padOff[l];
  const int t = threadIdx.x;
  const int lane = t & 63;
  const int wv = t >> 6;
  const int wco = wv & 1, wp = wv >> 1;
  const int coT = blockIdx.y;
  const int KS = CB * 9;

  const int ptile = (bx - d.tileStart[l]) * 64;
  const int ps = t & 63;
  {
  }
  int p = ptile + ps;
  int b = p / gg;
  int pr = p - b * gg;
  int y = pr / g;
  int x = pr - y * g;
  const int sbase = padOff + b * hp2 + (y + 1) * gp2 + (x + 1);
  const int cg = t >> 6;

  __shared__ uint4 BsHi[256];
  __shared__ uint4 BsLo[256];

  f32x4 acc00 = {0.f, 0.f, 0.f, 0.f}, acc01 = {0.f, 0.f, 0.f, 0.f};
  f32x4 acc10 = {0.f, 0.f, 0.f, 0.f}, acc11 = {0.f, 0.f, 0.f, 0.f};

  const size_t wbase =
      (size_t)coT * KS * 2048 + (size_t)wco * 512 + (size_t)lane * 8;
  const int fragP = wp * 32 + (lane & 15);
  const int kb = lane >> 4;

  // prologue prefetch: B (tap0,cb0), A (ks=0)
  u32 vv[8];
  {
    int soff = sbase - gp2 - 1;
    int ci0 = cg * 8;
#pragma unroll
    for (int j = 0; j < 8; j++) {
      u32 vvv = 0;
      if (!MASK || (ci0 + j) < CinBuf) vvv = actIn[(size_t)(ci0 + j) * PPT + soff];
      vv[j] = vvv;
    }
  }
  bf16x8 ah0 = *(const bf16x8*)(wHi + wbase);
  bf16x8 ah1 = *(const bf16x8*)(wHi + wbase + 1024);
  bf16x8 al0 = *(const bf16x8*)(wLo + wbase);
  bf16x8 al1 = *(const bf16x8*)(wLo + wbase + 1024);

  int tap = 0, cb = 0;
  for (int ks = 0; ks < KS; ++ks) {
    uint4 hq, lq;
    hq.x = __builtin_amdgcn_perm(vv[1], vv[0], 0x05040100u);
    hq.y = __builtin_amdgcn_perm(vv[3], vv[2], 0x05040100u);
    hq.z = __builtin_amdgcn_perm(vv[5], vv[4], 0x05040100u);
    hq.w = __builtin_amdgcn_perm(vv[7], vv[6], 0x05040100u);
    lq.x = __builtin_amdgcn_perm(vv[1], vv[0], 0x07060302u);
    lq.y = __builtin_amdgcn_perm(vv[3], vv[2], 0x07060302u);
    lq.z = __builtin_amdgcn_perm(vv[5], vv[4], 0x07060302u);
    lq.w = __builtin_amdgcn_perm(vv[7], vv[6], 0x07060302u);
    BsHi[t] = hq;
    BsLo[t] = lq;
    __syncthreads();

    // prefetch next step's B regs + A frags (hidden under MFMA below)
    bf16x8 ah0n, ah1n, al0n, al1n;
    const bool have = (ks + 1) < KS;
    int cbn = cb + 1, tapn = tap;
    if (cbn == CB) {
      cbn = 0;
      tapn = tap + 1;
    }
    if (have) {
      int t3 = (tapn * 11) >> 5;  // tapn/3 for 0..8
      int soffn = sbase + (t3 - 1) * gp2 + (tapn - 3 * t3 - 1);
      int ci0n = cbn * 32 + cg * 8;
#pragma unroll
      for (int j = 0; j < 8; j++) {
        u32 vvv = 0;
        if (!MASK || (ci0n + j) < CinBuf)
          vvv = actIn[(size_t)(ci0n + j) * PPT + soffn];
        vv[j] = vvv;
      }
      size_t wo = wbase + (size_t)(ks + 1) * 2048;
      ah0n = *(const bf16x8*)(wHi + wo);
      ah1n = *(const bf16x8*)(wHi + wo + 1024);
      al0n = *(const bf16x8*)(wLo + wo);
      al1n = *(const bf16x8*)(wLo + wo + 1024);
    }

    const int bi = (kb << 6) + fragP;
    bf16x8 bh0 = __builtin_bit_cast(bf16x8, BsHi[bi]);
    bf16x8 bh1 = __builtin_bit_cast(bf16x8, BsHi[bi + 16]);
    bf16x8 bl0 = __builtin_bit_cast(bf16x8, BsLo[bi]);
    bf16x8 bl1 = __builtin_bit_cast(bf16x8, BsLo[bi + 16]);

    acc00 = __builtin_amdgcn_mfma_f32_16x16x32_bf16(ah0, bh0, acc00, 0, 0, 0);
    acc00 = __builtin_amdgcn_mfma_f32_16x16x32_bf16(ah0, bl0, acc00, 0, 0, 0);
    acc00 = __builtin_amdgcn_mfma_f32_16x16x32_bf16(al0, bh0, acc00, 0, 0, 0);
    acc01 = __builtin_amdgcn_mfma_f32_16x16x32_bf16(ah0, bh1, acc01, 0, 0, 0);
    acc01 = __builtin_amdgcn_mfma_f32_16x16x32_bf16(ah0, bl1, acc01, 0, 0, 0);
    acc01 = __builtin_amdgcn_mfma_f32_16x16x32_bf16(al0, bh1, acc01, 0, 0, 0);
    acc10 = __builtin_amdgcn_mfma_f32_16x16x32_bf16(ah1, bh0, acc10, 0, 0, 0);
    acc10 = __builtin_amdgcn_mfma_f32_16x16x32_bf16(ah1, bl0, acc10, 0, 0, 0);
    acc10 = __builtin_amdgcn_mfma_f32_16x16x32_bf16(al1, bh0, acc10, 0, 0, 0);
    acc11 = __builtin_amdgcn_mfma_f32_16x16x32_bf16(ah1, bh1, acc11, 0, 0, 0);
    acc11 = __builtin_amdgcn_mfma_f32_16x16x32_bf16(ah1, bl1, acc11, 0, 0, 0);
    acc11 = __builtin_amdgcn_mfma_f32_16x16x32_bf16(al1, bh1, acc11, 0, 0, 0);
    __syncthreads();
    if (have) {
      ah0 = ah0n;
      ah1 = ah1n;
      al0 = al0n;
      al1 = al1n;
      tap = tapn;
      cb = cbn;
    }
  }

  // epilogue: bias + relu + split-pack + halo store
  int obase[2];
#pragma unroll
  for (int fp = 0; fp < 2; ++fp) {
    int po = ptile + wp * 32 + fp * 16 + (lane & 15);
    int bb = po / gg;
    int prr = po - bb * gg;
    int yy = prr / g;
    int xx = prr - yy * g;
    obase[fp] = padOff + bb * hp2 + (yy + 1) * gp2 + (xx + 1);
  }
  const int coBase = coT * 64 + wco * 32 + ((lane >> 4) << 2);
#pragma unroll
  for (int i = 0; i < 4; ++i) {
    {
      int co = coBase + i;
      float bbv = bias[co];
      float v0 = fmaxf(acc00[i] + bbv, 0.f);
      float v1 = fmaxf(acc01[i] + bbv, 0.f);
      actOut[(size_t)co * PPT + obase[0]] = packSplit(v0);
      actOut[(size_t)co * PPT + obase[1]] = packSplit(v1);
    }
    {
      int co = coBase + 16 + i;
      float bbv = bias[co];
      float v0 = fmaxf(acc10[i] + bbv, 0.f);
      float v1 = fmaxf(acc11[i] + bbv, 0.f);
      actOut[(size_t)co * PPT + obase[0]] = packSplit(v0);
      actOut[(size_t)co * PPT + obase[1]] = packSplit(v1);
    }
  }
}

// ---------------------------------------------------------------------------
// smpl head: 1x1 conv, Cout=157, +bias+init, NHWC out. scalar fp32.
// ---------------------------------------------------------------------------
struct HeadDesc {
  int tileStart[NLEV + 1];
  int padOff[NLEV];
  int g[NLEV];
  int outOff[NLEV];
};

__global__ __launch_bounds__(256) void head1x1(
    const u32* __restrict__ actIn, const float* __restrict__ w,
    const float* __restrict__ bias, const float* __restrict__ bias2,
    float* __restrict__ outB, HeadDesc d) {
  int bx = blockIdx.x;
  int l = 0;
#pragma unroll
  for (int i = 1; i < NLEV; i++)
    if (bx >= d.tileStart[i]) l = i;
  const int g = d.g[l];
  const int gp2 = g + 2, hp2 = gp2 * gp2, gg = g * g;
  const int t = threadIdx.x;
  const int ptile = (bx - d.tileStart[l]) * 64;
  const int pp = t & 63;
  int p = ptile + pp;
  int b = p / gg, pr = p - b * gg, y = pr / g, x = pr - y * g;
  const int hbase = d.padOff[l] + b * hp2 + (y + 1) * gp2 + (x + 1);
  const int co_tile = blockIdx.y * 64;
  __shared__ float As[32][68];
  __shared__ float Bs[32][68];
  const int tx = t & 15, ty = t >> 4;
  const int akk = t & 31, aco = t >> 5;
  const int kg = t >> 6;
  float acc[4][4];
#pragma unroll
  for (int i = 0; i < 4; i++)
#pragma unroll
    for (int j = 0; j < 4; j++) acc[i][j] = 0.f;

  for (int k0 = 0; k0 < 256; k0 += 32) {
#pragma unroll
    for (int i = 0; i < 8; i++) {
      int co = i * 8 + aco;
      int coG = co_tile + co;
      As[akk][co] = (coG < 157) ? w[(size_t)coG * 256 + k0 + akk] : 0.f;
    }
#pragma unroll
    for (int j = 0; j < 8; j++) {
      int kk = kg * 8 + j;
      Bs[kk][pp] = unpackSum(actIn[(size_t)(k0 + kk) * PPT + hbase]);
    }
    __syncthreads();
#pragma unroll
    for (int kk = 0; kk < 32; kk++) {
      float4 a4 = *reinterpret_cast<const float4*>(&As[kk][ty * 4]);
      float4 b4 = *reinterpret_cast<const float4*>(&Bs[kk][tx * 4]);
      float av[4] = {a4.x, a4.y, a4.z, a4.w};
      float bv[4] = {b4.x, b4.y, b4.z, b4.w};
#pragma unroll
      for (int i = 0; i < 4; i++)
#pragma unroll
        for (int j = 0; j < 4; j++) acc[i][j] = fmaf(av[i], bv[j], acc[i][j]);
    }
    __syncthreads();
  }
  const int co0 = co_tile + ty * 4;
#pragma unroll
  for (int i = 0; i < 4; i++) {
    int co = co0 + i;
    if (co < 157) {
      float bb = bias[co] + bias2[co];
#pragma unroll
      for (int j = 0; j < 4; j++) {
        int pg = ptile + tx * 4 + j;
        outB[d.outOff[l] + (size_t)pg * 157 + co] = acc[i][j] + bb;
      }
    }
  }
}

// ---------------------------------------------------------------------------
// cate head: 3x3 conv Cout=1 + sigmoid (halo in, flat heat out)
// ---------------------------------------------------------------------------
struct SmallDesc {
  int P[NLEV];
  int g[NLEV];
  int padOff[NLEV];
  int inOff[NLEV];
  int outOff[NLEV];
};

__global__ __launch_bounds__(256) void cate_head_all(
    const u32* __restrict__ actIn, const float* __restrict__ w,
    const float* __restrict__ bias, float* __restrict__ heat, SmallDesc d) {
  int l = blockIdx.y;
  int P = d.P[l], g = d.g[l];
  int gp2 = g + 2, hp2 = gp2 * gp2, gg = g * g;
  int t = threadIdx.x;
  int pi = t & 31, cw = t >> 5;
  int p = blockIdx.x * 32 + pi;
  bool ok = p < P;
  float s = 0.f;
  if (ok) {
    int b = p / gg, pr = p - b * gg, y = pr / g, x = pr - y * g;
    int hbase = d.padOff[l] + b * hp2 + (y + 1) * gp2 + (x + 1);
    for (int ci = cw * 32; ci < cw * 32 + 32; ci++) {
      const u32* pl = actIn + (size_t)ci * PPT + hbase;
      const float* wp = w + ci * 9;
#pragma unroll
      for (int tap = 0; tap < 9; tap++) {
        int dy = tap / 3 - 1;
        int dx = tap % 3 - 1;
        s += unpackSum(pl[dy * gp2 + dx]) * wp[tap];
      }
    }
  }
  __shared__ float red[256];
  red[t] = s;
  __syncthreads();
  if (cw == 0 && ok) {
    float tot = bias[0];
#pragma unroll
    for (int k2 = 0; k2 < 8; k2++) tot += red[k2 * 32 + pi];
    heat[d.outOff[l] + p] = 1.f / (1.f + expf(-tot));
  }
}

__global__ void nms_all(const float* __restrict__ heat, float* __restrict__ out,
                        SmallDesc d) {
  int l = blockIdx.y;
  int P = d.P[l], g = d.g[l];
  int gg = g * g;
  int p = blockIdx.x * 256 + threadIdx.x;
  if (p >= P) return;
  int pr = p % gg;
  int y = pr / g;
  int x = pr - y * g;
  const float* hb = heat + d.inOff[l];
  float c = hb[p], m = c;
  if (y > 0) {
    m = fmaxf(m, hb[p - g]);
    if (x > 0) m = fmaxf(m, hb[p - g - 1]);
  }
  if (x > 0) m = fmaxf(m, hb[p - 1]);
  out[d.outOff[l] + p] = (m == c) ? c : 0.f;
}

// ---------------------------------------------------------------------------
extern "C" void kernel_launch(void* const* d_in, const int* in_sizes, int n_in,
                              void* d_out, int out_size, void* d_ws, size_t ws_size,
                              hipStream_t stream) {
  const float* feat[5];
  for (int i = 0; i < 5; i++) feat[i] = (const float*)d_in[i];
  const float* smpl_w0 = (const float*)d_in[5];
  const float* smpl_b0 = (const float*)d_in[6];
  const float* smpl_w = (const float*)d_in[7];
  const float* smpl_b = (const float*)d_in[8];
  const float* cate_w0 = (const float*)d_in[9];
  const float* cate_b0 = (const float*)d_in[10];
  const float* cate_w = (const float*)d_in[11];
  const float* cate_b = (const float*)d_in[12];
  const float* cate_head_w = (const float*)d_in[13];
  const float* cate_head_b = (const float*)d_in[14];
  const float* smpl_head_w = (const float*)d_in[15];
  const float* smpl_head_b = (const float*)d_in[16];
  const float* smpl_init = (const float*)d_in[17];
  float* out = (float*)d_out;

  static const int GR[5] = {40, 36, 24, 16, 12};
  static const int SH[5] = {200, 100, 50, 25, 13};
  static const int MIDW[5] = {100, 0, 0, 0, 25};

  int P[5], cumP[6], tS[6], padOff[5];
  cumP[0] = 0;
  tS[0] = 0;
  int po = 0;
  for (int l = 0; l < 5; l++) {
    P[l] = 4 * GR[l] * GR[l];
    cumP[l + 1] = cumP[l] + P[l];
    tS[l + 1] = tS[l] + P[l] / 64;
    padOff[l] = po;
    po += 4 * (GR[l] + 2) * (GR[l] + 2);
  }
  // po == PPT

  int smpl_off[5], cate_off[5];
  {
    int off = 0;
    for (int l = 0; l < 5; l++) {
      smpl_off[l] = off;
      off += P[l] * 157;
    }
    for (int l = 0; l < 5; l++) {
      cate_off[l] = off;
      off += P[l];
    }
  }

  // workspace layout
  u32* bufA = (u32*)d_ws;                    // 264 ch
  u32* bufB = bufA + (size_t)264 * PPT;      // 256 ch
  u32* bufC = bufB + (size_t)256 * PPT;      // 256 ch
  float* heat = (float*)(bufC + (size_t)256 * PPT);
  const size_t WTOT = (size_t)(81 + 7 * 72) * 8192;  // 4,792,320 elems
  u16* wHi = (u16*)(heat + 15488);
  u16* wLo = wHi + WTOT;
  const size_t ACT_BYTES = (size_t)(264 + 256 + 256) * PPT * 4 + 15488 * 4;

  // zero act buffers (halos + pad channels); weights fully rewritten by prep
  hipMemsetAsync(d_ws, 0, ACT_BYTES, stream);

  // weight prep
  PrepDesc pd;
  const size_t LSTR = (size_t)256 * 256 * 9;
  pd.src[0] = smpl_w0;  pd.Cin[0] = 258;  pd.CB[0] = 9;
  pd.src[1] = smpl_w;   pd.Cin[1] = 256;  pd.CB[1] = 8;
  pd.src[2] = smpl_w + LSTR;     pd.Cin[2] = 256; pd.CB[2] = 8;
  pd.src[3] = smpl_w + 2 * LSTR; pd.Cin[3] = 256; pd.CB[3] = 8;
  pd.src[4] = cate_w0;  pd.Cin[4] = 256;  pd.CB[4] = 8;
  pd.src[5] = cate_w;   pd.Cin[5] = 256;  pd.CB[5] = 8;
  pd.src[6] = cate_w + LSTR;     pd.Cin[6] = 256; pd.CB[6] = 8;
  pd.src[7] = cate_w + 2 * LSTR; pd.Cin[7] = 256; pd.CB[7] = 8;
  {
    int off = 0;
    for (int i = 0; i < 8; i++) {
      pd.dstOff[i] = off;
      off += pd.CB[i] * 9 * 8192;
    }
  }
  hipLaunchKernelGGL(prep_weights, dim3(81 * 32, 8), dim3(256), 0, stream, pd, wHi,
                     wLo);

  // build inputs
  BuildDesc bd;
  for (int l = 0; l < 5; l++) {
    bd.src[l] = feat[l];
    bd.H[l] = SH[l];
    bd.mid[l] = MIDW[l];
    bd.P[l] = P[l];
    bd.g[l] = GR[l];
    bd.padOff[l] = padOff[l];
  }
  hipLaunchKernelGGL(build_all, dim3((258 * P[0] + 255) / 256, 5), dim3(256), 0,
                     stream, bd, bufA);

  ConvDesc cd;
  HeadDesc hd;
  SmallDesc sd, nd;
  for (int i = 0; i <= 5; i++) {
    cd.tileStart[i] = tS[i];
    hd.tileStart[i] = tS[i];
  }
  for (int l = 0; l < 5; l++) {
    cd.padOff[l] = padOff[l];
    cd.g[l] = GR[l];
    hd.padOff[l] = padOff[l];
    hd.g[l] = GR[l];
    hd.outOff[l] = smpl_off[l];
    sd.P[l] = P[l];
    sd.g[l] = GR[l];
    sd.padOff[l] = padOff[l];
    sd.inOff[l] = 0;
    sd.outOff[l] = cumP[l];
    nd.P[l] = P[l];
    nd.g[l] = GR[l];
    nd.padOff[l] = 0;
    nd.inOff[l] = cumP[l];
    nd.outOff[l] = cate_off[l];
  }

  const int NT = tS[5];  // 242
  dim3 cg(NT, 4);
  // ---- smpl tower ----
  hipLaunchKernelGGL(conv_mfma<true>, cg, dim3(256), 0, stream, bufA, wHi + pd.dstOff[0],
                     wLo + pd.dstOff[0], smpl_b0, bufB, cd, 9, 264);
  hipLaunchKernelGGL(conv_mfma<false>, cg, dim3(256), 0, stream, bufB,
                     wHi + pd.dstOff[1], wLo + pd.dstOff[1], smpl_b + 0, bufC, cd, 8,
                     256);
  hipLaunchKernelGGL(conv_mfma<false>, cg, dim3(256), 0, stream, bufC,
                     wHi + pd.dstOff[2], wLo + pd.dstOff[2], smpl_b + 256, bufB, cd, 8,
                     256);
  hipLaunchKernelGGL(conv_mfma<false>, cg, dim3(256), 0, stream, bufB,
                     wHi + pd.dstOff[3], wLo + pd.dstOff[3], smpl_b + 512, bufC, cd, 8,
                     256);
  hipLaunchKernelGGL(head1x1, dim3(NT, 3), dim3(256), 0, stream, bufC, smpl_head_w,
                     smpl_head_b, smpl_init, out, hd);
  // ---- cate tower ----
  hipLaunchKernelGGL(conv_mfma<false>, cg, dim3(256), 0, stream, bufA,
                     wHi + pd.dstOff[4], wLo + pd.dstOff[4], cate_b0, bufB, cd, 8, 256);
  hipLaunchKernelGGL(conv_mfma<false>, cg, dim3(256), 0, stream, bufB,
                     wHi + pd.dstOff[5], wLo + pd.dstOff[5], cate_b + 0, bufC, cd, 8,
                     256);
  hipLaunchKernelGGL(conv_mfma<false>, cg, dim3(256), 0, stream, bufC,
                     wHi + pd.dstOff[6], wLo + pd.dstOff[6], cate_b + 256, bufB, cd, 8,
                     256);
  hipLaunchKernelGGL(conv_mfma<false>, cg, dim3(256), 0, stream, bufB,
                     wHi + pd.dstOff[7], wLo + pd.dstOff[7], cate_b + 512, bufC, cd, 8,
                     256);
  hipLaunchKernelGGL(cate_head_all, dim3((P[0] + 31) / 32, 5), dim3(256), 0, stream,
                     bufC, cate_head_w, cate_head_b, heat, sd);
  hipLaunchKernelGGL(nms_all, dim3((P[0] + 255) / 256, 5), dim3(256), 0, stream, heat,
                     out, nd);
  (void)in_sizes;
  (void)n_in;
  (void)out_size;
  (void)ws_size;
}

// Round 4
// 795.002 us; speedup vs baseline: 20.7378x; 1.5358x over previous
//
#include <hip/hip_runtime.h>
#include <math.h>
#include <stdint.h>

#define NLEV 5
#define PPT 17616  // sum over levels of 4*(g+2)^2

typedef __attribute__((ext_vector_type(8))) __bf16 bf16x8;
typedef __attribute__((ext_vector_type(4))) float f32x4;
typedef unsigned int u32;
typedef unsigned short u16;

__device__ __forceinline__ u32 f2bf(float f) {
  u32 u = __builtin_bit_cast(u32, f);
  return (u + 0x7FFFu + ((u >> 16) & 1u)) >> 16;
}
__device__ __forceinline__ u32 packSplit(float v) {
  u32 hi = f2bf(v);
  float fhi = __builtin_bit_cast(float, hi << 16);
  u32 lo = f2bf(v - fhi);
  return hi | (lo << 16);
}
__device__ __forceinline__ float unpackSum(u32 w) {
  return __builtin_bit_cast(float, w << 16) +
         __builtin_bit_cast(float, w & 0xFFFF0000u);
}

// Activation layout: u32 element (hi|lo bf16 packed) at
//   [(c>>3)*PPT + halo_px]*8 + (c&7)
// so one pixel's 8-channel granule is 32B contiguous.

// ---------------------------------------------------------------------------
// Weight prep: fp32 [Cout][Cin][3][3] -> MFMA A-frag layout, hi/lo bf16 planes.
// K-order is cb-major, tap-minor: ks = cb*9 + tap.
// elem offset = ((((coT*KS + ks)*2 + f)*2 + wco)*64 + lane)*8 + j
// co = coT*64+wco*32+f*16+(lane&15); ci = cb*32+(lane>>4)*8+j
// ---------------------------------------------------------------------------
struct PrepDesc {
  const float* src[8];
  int Cin[8];
  int CB[8];
  int dstOff[8];
};

__global__ __launch_bounds__(256) void prep_weights(PrepDesc pd, u16* __restrict__ wHi,
                                                    u16* __restrict__ wLo) {
  int cfg = blockIdx.y;
  int CB = pd.CB[cfg];
  int KS = CB * 9;
  int total = KS * 8192;
  int didx = blockIdx.x * 256 + threadIdx.x;
  if (didx >= total) return;
  int j = didx & 7;
  int lane = (didx >> 3) & 63;
  int wco = (didx >> 9) & 1;
  int f = (didx >> 10) & 1;
  int rest = didx >> 11;
  int ks = rest % KS;
  int coT = rest / KS;
  int cb = ks / 9;            // cb-major
  int tap = ks - cb * 9;
  int ci = cb * 32 + ((lane >> 4) << 3) + j;
  int co = coT * 64 + wco * 32 + f * 16 + (lane & 15);
  int Cin = pd.Cin[cfg];
  float v = 0.f;
  if (ci < Cin) v = pd.src[cfg][((size_t)co * Cin + ci) * 9 + tap];
  u32 hi = f2bf(v);
  float fhi = __builtin_bit_cast(float, hi << 16);
  u32 lo = f2bf(v - fhi);
  wHi[pd.dstOff[cfg] + didx] = (u16)hi;
  wLo[pd.dstOff[cfg] + didx] = (u16)lo;
}

// ---------------------------------------------------------------------------
// build: resize (optionally fused double resize) + coord ramps -> halo acts
// ---------------------------------------------------------------------------
struct BuildDesc {
  const float* src[NLEV];
  int H[NLEV];
  int mid[NLEV];
  int P[NLEV];
  int g[NLEV];
  int padOff[NLEV];
};

__device__ __forceinline__ float bsample(const float* __restrict__ pl, int H, int W,
                                         float fy, float fx) {
  int y0 = (int)floorf(fy);
  int y1 = min(y0 + 1, H - 1);
  float wy = fy - (float)y0;
  int x0 = (int)floorf(fx);
  int x1 = min(x0 + 1, W - 1);
  float wx = fx - (float)x0;
  const float* r0 = pl + (size_t)y0 * W;
  const float* r1 = pl + (size_t)y1 * W;
  float top = r0[x0] * (1.f - wx) + r0[x1] * wx;
  float bot = r1[x0] * (1.f - wx) + r1[x1] * wx;
  return top * (1.f - wy) + bot * wy;
}

__global__ __launch_bounds__(256) void build_all(BuildDesc bd, u32* __restrict__ dst) {
  int l = blockIdx.y;
  int P = bd.P[l];
  int g = bd.g[l];
  int total = 258 * P;
  int idx = blockIdx.x * 256 + threadIdx.x;
  if (idx >= total) return;
  int c = idx / P;
  int p = idx - c * P;
  int gg = g * g;
  int b = p / gg;
  int pr = p - b * gg;
  int i = pr / g;
  int j = pr - i * g;
  float val;
  if (c >= 256) {
    int tt = (c == 256) ? j : i;
    val = -1.f + 2.f * (float)tt / (float)(g - 1);
  } else {
    int H = bd.H[l], W = bd.H[l];
    int mid = bd.mid[l];
    const float* pl = bd.src[l] + ((size_t)b * 256 + c) * H * W;
    if (!mid) {
      float fy = (float)i * (float)(H - 1) / (float)(g - 1);
      float fx = (float)j * (float)(W - 1) / (float)(g - 1);
      val = bsample(pl, H, W, fy, fx);
    } else {
      int midh = mid, midw = mid;
      float fym = (float)i * (float)(midh - 1) / (float)(g - 1);
      float fxm = (float)j * (float)(midw - 1) / (float)(g - 1);
      int y0 = (int)floorf(fym);
      int y1 = min(y0 + 1, midh - 1);
      float wy = fym - (float)y0;
      int x0 = (int)floorf(fxm);
      int x1 = min(x0 + 1, midw - 1);
      float wx = fxm - (float)x0;
      float sy0 = (float)y0 * (float)(H - 1) / (float)(midh - 1);
      float sy1 = (float)y1 * (float)(H - 1) / (float)(midh - 1);
      float sx0 = (float)x0 * (float)(W - 1) / (float)(midw - 1);
      float sx1 = (float)x1 * (float)(W - 1) / (float)(midw - 1);
      float v00 = bsample(pl, H, W, sy0, sx0);
      float v01 = bsample(pl, H, W, sy0, sx1);
      float v10 = bsample(pl, H, W, sy1, sx0);
      float v11 = bsample(pl, H, W, sy1, sx1);
      float top = v00 * (1.f - wx) + v01 * wx;
      float bot = v10 * (1.f - wx) + v11 * wx;
      val = top * (1.f - wy) + bot * wy;
    }
  }
  int gp2 = g + 2;
  int hpos = bd.padOff[l] + b * gp2 * gp2 + (i + 1) * gp2 + (j + 1);
  dst[((size_t)(c >> 3) * PPT + hpos) * 8 + (c & 7)] = packSplit(val);
}

// ---------------------------------------------------------------------------
// MFMA conv 3x3: 64co x 64px tile, 4 waves (2co x 2p), split-bf16 (3 MFMA).
// cb-major K order; XCD-pinned tiles; granule act layout.
// ---------------------------------------------------------------------------
struct ConvDesc {
  int tileStart[NLEV + 1];
  int padOff[NLEV];
  int g[NLEV];
};

template <bool MASK>
__global__ __launch_bounds__(256) void conv_mfma(
    const u32* __restrict__ actIn, const u16* __restrict__ wHi,
    const u16* __restrict__ wLo, const float* __restrict__ bias,
    u32* __restrict__ actOut, ConvDesc d, int CB, int CinBuf) {
  // XCD-aware decode: 992 blocks; xcd slice owns tiles {xcd, xcd+8, ...} x 4 coT
  const int bid = blockIdx.x;
  const int xcd = bid & 7;
  const int i6 = bid >> 3;         // 0..123
  const int coT = i6 & 3;
  const int tile = xcd + (i6 >> 2) * 8;
  const int NT = d.tileStart[NLEV];
  if (tile >= NT) return;

  int l = 0;
#pragma unroll
  for (int i = 1; i < NLEV; i++)
    if (tile >= d.tileStart[i]) l = i;
  const int g = d.g[l];
  const int gp2 = g + 2;
  const int hp2 = gp2 * gp2;
  const int gg = g * g;
  const int padOff = d.padOff[l];
  const int t = threadIdx.x;
  const int lane = t & 63;
  const int wv = t >> 6;
  const int wco = wv & 1, wp = wv >> 1;
  const int KS = CB * 9;
  const int NG = CinBuf >> 3;

  const int ptile = (tile - d.tileStart[l]) * 64;
  const int ps = t & 63;
  int p = ptile + ps;
  int b = p / gg;
  int pr = p - b * gg;
  int y = pr / g;
  int x = pr - y * g;
  const int sbase = padOff + b * hp2 + (y + 1) * gp2 + (x + 1);
  const int cg = t >> 6;  // wave id == B granule within 32-ci block

  __shared__ uint4 BsHi[256];
  __shared__ uint4 BsLo[256];

  f32x4 acc00 = {0.f, 0.f, 0.f, 0.f}, acc01 = {0.f, 0.f, 0.f, 0.f};
  f32x4 acc10 = {0.f, 0.f, 0.f, 0.f}, acc11 = {0.f, 0.f, 0.f, 0.f};

  const size_t wbase =
      (size_t)coT * KS * 2048 + (size_t)wco * 512 + (size_t)lane * 8;
  const int fragP = wp * 32 + (lane & 15);
  const int kb = lane >> 4;

  // prologue prefetch: B (cb0, tap0), A (ks=0)
  uint4 q0, q1;
  {
    int soff = sbase - gp2 - 1;
    const u32* bp = actIn + ((size_t)cg * PPT + soff) * 8;
    q0 = *(const uint4*)bp;
    q1 = *(const uint4*)(bp + 4);
  }
  bf16x8 ah0 = *(const bf16x8*)(wHi + wbase);
  bf16x8 ah1 = *(const bf16x8*)(wHi + wbase + 1024);
  bf16x8 al0 = *(const bf16x8*)(wLo + wbase);
  bf16x8 al1 = *(const bf16x8*)(wLo + wbase + 1024);

  int tap = 0, cb = 0;
  for (int ks = 0; ks < KS; ++ks) {
    uint4 hq, lq;
    hq.x = __builtin_amdgcn_perm(q0.y, q0.x, 0x05040100u);
    hq.y = __builtin_amdgcn_perm(q0.w, q0.z, 0x05040100u);
    hq.z = __builtin_amdgcn_perm(q1.y, q1.x, 0x05040100u);
    hq.w = __builtin_amdgcn_perm(q1.w, q1.z, 0x05040100u);
    lq.x = __builtin_amdgcn_perm(q0.y, q0.x, 0x07060302u);
    lq.y = __builtin_amdgcn_perm(q0.w, q0.z, 0x07060302u);
    lq.z = __builtin_amdgcn_perm(q1.y, q1.x, 0x07060302u);
    lq.w = __builtin_amdgcn_perm(q1.w, q1.z, 0x07060302u);
    BsHi[t] = hq;
    BsLo[t] = lq;
    __syncthreads();

    // prefetch next step (hidden under MFMA below)
    bf16x8 ah0n, ah1n, al0n, al1n;
    uint4 q0n = {0, 0, 0, 0}, q1n = {0, 0, 0, 0};
    const bool have = (ks + 1) < KS;
    int tapn = tap + 1, cbn = cb;
    if (tapn == 9) {
      tapn = 0;
      cbn++;
    }
    if (have) {
      int t3 = (tapn * 11) >> 5;  // tapn/3 for 0..8
      int soffn = sbase + (t3 - 1) * gp2 + (tapn - 3 * t3 - 1);
      int gan = cbn * 4 + cg;
      if (!MASK || gan < NG) {
        const u32* bp = actIn + ((size_t)gan * PPT + soffn) * 8;
        q0n = *(const uint4*)bp;
        q1n = *(const uint4*)(bp + 4);
      }
      size_t wo = wbase + (size_t)(ks + 1) * 2048;
      ah0n = *(const bf16x8*)(wHi + wo);
      ah1n = *(const bf16x8*)(wHi + wo + 1024);
      al0n = *(const bf16x8*)(wLo + wo);
      al1n = *(const bf16x8*)(wLo + wo + 1024);
    }

    const int bi = (kb << 6) + fragP;
    bf16x8 bh0 = __builtin_bit_cast(bf16x8, BsHi[bi]);
    bf16x8 bh1 = __builtin_bit_cast(bf16x8, BsHi[bi + 16]);
    bf16x8 bl0 = __builtin_bit_cast(bf16x8, BsLo[bi]);
    bf16x8 bl1 = __builtin_bit_cast(bf16x8, BsLo[bi + 16]);

    acc00 = __builtin_amdgcn_mfma_f32_16x16x32_bf16(ah0, bh0, acc00, 0, 0, 0);
    acc00 = __builtin_amdgcn_mfma_f32_16x16x32_bf16(ah0, bl0, acc00, 0, 0, 0);
    acc00 = __builtin_amdgcn_mfma_f32_16x16x32_bf16(al0, bh0, acc00, 0, 0, 0);
    acc01 = __builtin_amdgcn_mfma_f32_16x16x32_bf16(ah0, bh1, acc01, 0, 0, 0);
    acc01 = __builtin_amdgcn_mfma_f32_16x16x32_bf16(ah0, bl1, acc01, 0, 0, 0);
    acc01 = __builtin_amdgcn_mfma_f32_16x16x32_bf16(al0, bh1, acc01, 0, 0, 0);
    acc10 = __builtin_amdgcn_mfma_f32_16x16x32_bf16(ah1, bh0, acc10, 0, 0, 0);
    acc10 = __builtin_amdgcn_mfma_f32_16x16x32_bf16(ah1, bl0, acc10, 0, 0, 0);
    acc10 = __builtin_amdgcn_mfma_f32_16x16x32_bf16(al1, bh0, acc10, 0, 0, 0);
    acc11 = __builtin_amdgcn_mfma_f32_16x16x32_bf16(ah1, bh1, acc11, 0, 0, 0);
    acc11 = __builtin_amdgcn_mfma_f32_16x16x32_bf16(ah1, bl1, acc11, 0, 0, 0);
    acc11 = __builtin_amdgcn_mfma_f32_16x16x32_bf16(al1, bh1, acc11, 0, 0, 0);
    __syncthreads();
    if (have) {
      ah0 = ah0n;
      ah1 = ah1n;
      al0 = al0n;
      al1 = al1n;
      q0 = q0n;
      q1 = q1n;
      tap = tapn;
      cb = cbn;
    }
  }

  // epilogue: bias + relu + split-pack + granule halo store (dwordx4)
  int obase[2];
#pragma unroll
  for (int fp = 0; fp < 2; ++fp) {
    int po = ptile + wp * 32 + fp * 16 + (lane & 15);
    int bb = po / gg;
    int prr = po - bb * gg;
    int yy = prr / g;
    int xx = prr - yy * g;
    obase[fp] = padOff + bb * hp2 + (yy + 1) * gp2 + (xx + 1);
  }
  const int coBase = coT * 64 + wco * 32 + ((lane >> 4) << 2);
  float4 bA = *(const float4*)(bias + coBase);
  float4 bB = *(const float4*)(bias + coBase + 16);
  const size_t rowA = (size_t)(coBase >> 3) * PPT;
  const size_t rowB = (size_t)((coBase + 16) >> 3) * PPT;
  const int sub = coBase & 7;
  uint4 s;
  s.x = packSplit(fmaxf(acc00[0] + bA.x, 0.f));
  s.y = packSplit(fmaxf(acc00[1] + bA.y, 0.f));
  s.z = packSplit(fmaxf(acc00[2] + bA.z, 0.f));
  s.w = packSplit(fmaxf(acc00[3] + bA.w, 0.f));
  *(uint4*)(actOut + (rowA + obase[0]) * 8 + sub) = s;
  s.x = packSplit(fmaxf(acc01[0] + bA.x, 0.f));
  s.y = packSplit(fmaxf(acc01[1] + bA.y, 0.f));
  s.z = packSplit(fmaxf(acc01[2] + bA.z, 0.f));
  s.w = packSplit(fmaxf(acc01[3] + bA.w, 0.f));
  *(uint4*)(actOut + (rowA + obase[1]) * 8 + sub) = s;
  s.x = packSplit(fmaxf(acc10[0] + bB.x, 0.f));
  s.y = packSplit(fmaxf(acc10[1] + bB.y, 0.f));
  s.z = packSplit(fmaxf(acc10[2] + bB.z, 0.f));
  s.w = packSplit(fmaxf(acc10[3] + bB.w, 0.f));
  *(uint4*)(actOut + (rowB + obase[0]) * 8 + sub) = s;
  s.x = packSplit(fmaxf(acc11[0] + bB.x, 0.f));
  s.y = packSplit(fmaxf(acc11[1] + bB.y, 0.f));
  s.z = packSplit(fmaxf(acc11[2] + bB.z, 0.f));
  s.w = packSplit(fmaxf(acc11[3] + bB.w, 0.f));
  *(uint4*)(actOut + (rowB + obase[1]) * 8 + sub) = s;
}

// ---------------------------------------------------------------------------
// smpl head: 1x1 conv, Cout=157, +bias+init, NHWC out. scalar fp32.
// ---------------------------------------------------------------------------
struct HeadDesc {
  int tileStart[NLEV + 1];
  int padOff[NLEV];
  int g[NLEV];
  int outOff[NLEV];
};

__global__ __launch_bounds__(256) void head1x1(
    const u32* __restrict__ actIn, const float* __restrict__ w,
    const float* __restrict__ bias, const float* __restrict__ bias2,
    float* __restrict__ outB, HeadDesc d) {
  int bx = blockIdx.x;
  int l = 0;
#pragma unroll
  for (int i = 1; i < NLEV; i++)
    if (bx >= d.tileStart[i]) l = i;
  const int g = d.g[l];
  const int gp2 = g + 2, hp2 = gp2 * gp2, gg = g * g;
  const int t = threadIdx.x;
  const int ptile = (bx - d.tileStart[l]) * 64;
  const int pp = t & 63;
  int p = ptile + pp;
  int b = p / gg, pr = p - b * gg, y = pr / g, x = pr - y * g;
  const int hbase = d.padOff[l] + b * hp2 + (y + 1) * gp2 + (x + 1);
  const int co_tile = blockIdx.y * 64;
  __shared__ float As[32][68];
  __shared__ float Bs[32][68];
  const int tx = t & 15, ty = t >> 4;
  const int akk = t & 31, aco = t >> 5;
  const int kg = t >> 6;
  float acc[4][4];
#pragma unroll
  for (int i = 0; i < 4; i++)
#pragma unroll
    for (int j = 0; j < 4; j++) acc[i][j] = 0.f;

  for (int k0 = 0; k0 < 256; k0 += 32) {
#pragma unroll
    for (int i = 0; i < 8; i++) {
      int co = i * 8 + aco;
      int coG = co_tile + co;
      As[akk][co] = (coG < 157) ? w[(size_t)coG * 256 + k0 + akk] : 0.f;
    }
    {
      const u32* src = actIn + (((size_t)(k0 >> 3) + kg) * PPT + hbase) * 8;
#pragma unroll
      for (int j = 0; j < 8; j++) Bs[kg * 8 + j][pp] = unpackSum(src[j]);
    }
    __syncthreads();
#pragma unroll
    for (int kk = 0; kk < 32; kk++) {
      float4 a4 = *reinterpret_cast<const float4*>(&As[kk][ty * 4]);
      float4 b4 = *reinterpret_cast<const float4*>(&Bs[kk][tx * 4]);
      float av[4] = {a4.x, a4.y, a4.z, a4.w};
      float bv[4] = {b4.x, b4.y, b4.z, b4.w};
#pragma unroll
      for (int i = 0; i < 4; i++)
#pragma unroll
        for (int j = 0; j < 4; j++) acc[i][j] = fmaf(av[i], bv[j], acc[i][j]);
    }
    __syncthreads();
  }
  const int co0 = co_tile + ty * 4;
#pragma unroll
  for (int i = 0; i < 4; i++) {
    int co = co0 + i;
    if (co < 157) {
      float bb = bias[co] + bias2[co];
#pragma unroll
      for (int j = 0; j < 4; j++) {
        int pg = ptile + tx * 4 + j;
        outB[d.outOff[l] + (size_t)pg * 157 + co] = acc[i][j] + bb;
      }
    }
  }
}

// ---------------------------------------------------------------------------
// cate head: 3x3 conv Cout=1 + sigmoid (halo granule in, flat heat out)
// ---------------------------------------------------------------------------
struct SmallDesc {
  int P[NLEV];
  int g[NLEV];
  int padOff[NLEV];
  int inOff[NLEV];
  int outOff[NLEV];
};

__global__ __launch_bounds__(256) void cate_head_all(
    const u32* __restrict__ actIn, const float* __restrict__ w,
    const float* __restrict__ bias, float* __restrict__ heat, SmallDesc d) {
  int l = blockIdx.y;
  int P = d.P[l], g = d.g[l];
  int gp2 = g + 2, hp2 = gp2 * gp2, gg = g * g;
  int t = threadIdx.x;
  int pi = t & 31, cw = t >> 5;
  int p = blockIdx.x * 32 + pi;
  bool ok = p < P;
  float s = 0.f;
  if (ok) {
    int b = p / gg, pr = p - b * gg, y = pr / g, x = pr - y * g;
    int hbase = d.padOff[l] + b * hp2 + (y + 1) * gp2 + (x + 1);
    for (int ci = cw * 32; ci < cw * 32 + 32; ci++) {
      const u32* pl = actIn + ((size_t)(ci >> 3) * PPT + hbase) * 8 + (ci & 7);
      const float* wp = w + ci * 9;
#pragma unroll
      for (int tap = 0; tap < 9; tap++) {
        int dy = tap / 3 - 1;
        int dx = tap % 3 - 1;
        s += unpackSum(pl[(dy * gp2 + dx) * 8]) * wp[tap];
      }
    }
  }
  __shared__ float red[256];
  red[t] = s;
  __syncthreads();
  if (cw == 0 && ok) {
    float tot = bias[0];
#pragma unroll
    for (int k2 = 0; k2 < 8; k2++) tot += red[k2 * 32 + pi];
    heat[d.outOff[l] + p] = 1.f / (1.f + expf(-tot));
  }
}

__global__ void nms_all(const float* __restrict__ heat, float* __restrict__ out,
                        SmallDesc d) {
  int l = blockIdx.y;
  int P = d.P[l], g = d.g[l];
  int gg = g * g;
  int p = blockIdx.x * 256 + threadIdx.x;
  if (p >= P) return;
  int pr = p % gg;
  int y = pr / g;
  int x = pr - y * g;
  const float* hb = heat + d.inOff[l];
  float c = hb[p], m = c;
  if (y > 0) {
    m = fmaxf(m, hb[p - g]);
    if (x > 0) m = fmaxf(m, hb[p - g - 1]);
  }
  if (x > 0) m = fmaxf(m, hb[p - 1]);
  out[d.outOff[l] + p] = (m == c) ? c : 0.f;
}

// ---------------------------------------------------------------------------
extern "C" void kernel_launch(void* const* d_in, const int* in_sizes, int n_in,
                              void* d_out, int out_size, void* d_ws, size_t ws_size,
                              hipStream_t stream) {
  const float* feat[5];
  for (int i = 0; i < 5; i++) feat[i] = (const float*)d_in[i];
  const float* smpl_w0 = (const float*)d_in[5];
  const float* smpl_b0 = (const float*)d_in[6];
  const float* smpl_w = (const float*)d_in[7];
  const float* smpl_b = (const float*)d_in[8];
  const float* cate_w0 = (const float*)d_in[9];
  const float* cate_b0 = (const float*)d_in[10];
  const float* cate_w = (const float*)d_in[11];
  const float* cate_b = (const float*)d_in[12];
  const float* cate_head_w = (const float*)d_in[13];
  const float* cate_head_b = (const float*)d_in[14];
  const float* smpl_head_w = (const float*)d_in[15];
  const float* smpl_head_b = (const float*)d_in[16];
  const float* smpl_init = (const float*)d_in[17];
  float* out = (float*)d_out;

  static const int GR[5] = {40, 36, 24, 16, 12};
  static const int SH[5] = {200, 100, 50, 25, 13};
  static const int MIDW[5] = {100, 0, 0, 0, 25};

  int P[5], cumP[6], tS[6], padOff[5];
  cumP[0] = 0;
  tS[0] = 0;
  int po = 0;
  for (int l = 0; l < 5; l++) {
    P[l] = 4 * GR[l] * GR[l];
    cumP[l + 1] = cumP[l] + P[l];
    tS[l + 1] = tS[l] + P[l] / 64;
    padOff[l] = po;
    po += 4 * (GR[l] + 2) * (GR[l] + 2);
  }
  // po == PPT

  int smpl_off[5], cate_off[5];
  {
    int off = 0;
    for (int l = 0; l < 5; l++) {
      smpl_off[l] = off;
      off += P[l] * 157;
    }
    for (int l = 0; l < 5; l++) {
      cate_off[l] = off;
      off += P[l];
    }
  }

  // workspace layout (u32 units): bufA 33 granule-rows, bufB/C 32 each
  u32* bufA = (u32*)d_ws;
  u32* bufB = bufA + (size_t)33 * PPT * 8;
  u32* bufC = bufB + (size_t)32 * PPT * 8;
  float* heat = (float*)(bufC + (size_t)32 * PPT * 8);
  const size_t WTOT = (size_t)(81 + 7 * 72) * 8192;
  u16* wHi = (u16*)(heat + 15488);
  u16* wLo = wHi + WTOT;
  const size_t ACT_BYTES = (size_t)(33 + 32 + 32) * PPT * 8 * 4 + 15488 * 4;

  hipMemsetAsync(d_ws, 0, ACT_BYTES, stream);

  // weight prep
  PrepDesc pd;
  const size_t LSTR = (size_t)256 * 256 * 9;
  pd.src[0] = smpl_w0;  pd.Cin[0] = 258;  pd.CB[0] = 9;
  pd.src[1] = smpl_w;   pd.Cin[1] = 256;  pd.CB[1] = 8;
  pd.src[2] = smpl_w + LSTR;     pd.Cin[2] = 256; pd.CB[2] = 8;
  pd.src[3] = smpl_w + 2 * LSTR; pd.Cin[3] = 256; pd.CB[3] = 8;
  pd.src[4] = cate_w0;  pd.Cin[4] = 256;  pd.CB[4] = 8;
  pd.src[5] = cate_w;   pd.Cin[5] = 256;  pd.CB[5] = 8;
  pd.src[6] = cate_w + LSTR;     pd.Cin[6] = 256; pd.CB[6] = 8;
  pd.src[7] = cate_w + 2 * LSTR; pd.Cin[7] = 256; pd.CB[7] = 8;
  {
    int off = 0;
    for (int i = 0; i < 8; i++) {
      pd.dstOff[i] = off;
      off += pd.CB[i] * 9 * 8192;
    }
  }
  hipLaunchKernelGGL(prep_weights, dim3(81 * 32, 8), dim3(256), 0, stream, pd, wHi,
                     wLo);

  // build inputs
  BuildDesc bd;
  for (int l = 0; l < 5; l++) {
    bd.src[l] = feat[l];
    bd.H[l] = SH[l];
    bd.mid[l] = MIDW[l];
    bd.P[l] = P[l];
    bd.g[l] = GR[l];
    bd.padOff[l] = padOff[l];
  }
  hipLaunchKernelGGL(build_all, dim3((258 * P[0] + 255) / 256, 5), dim3(256), 0,
                     stream, bd, bufA);

  ConvDesc cd;
  HeadDesc hd;
  SmallDesc sd, nd;
  for (int i = 0; i <= 5; i++) {
    cd.tileStart[i] = tS[i];
    hd.tileStart[i] = tS[i];
  }
  for (int l = 0; l < 5; l++) {
    cd.padOff[l] = padOff[l];
    cd.g[l] = GR[l];
    hd.padOff[l] = padOff[l];
    hd.g[l] = GR[l];
    hd.outOff[l] = smpl_off[l];
    sd.P[l] = P[l];
    sd.g[l] = GR[l];
    sd.padOff[l] = padOff[l];
    sd.inOff[l] = 0;
    sd.outOff[l] = cumP[l];
    nd.P[l] = P[l];
    nd.g[l] = GR[l];
    nd.padOff[l] = 0;
    nd.inOff[l] = cumP[l];
    nd.outOff[l] = cate_off[l];
  }

  const int NT = tS[5];       // 242
  const int CGRID = 8 * 124;  // 992 blocks: 8 xcd slots x (31 tiles x 4 coT)
  // ---- smpl tower ----
  hipLaunchKernelGGL(conv_mfma<true>, dim3(CGRID), dim3(256), 0, stream, bufA,
                     wHi + pd.dstOff[0], wLo + pd.dstOff[0], smpl_b0, bufB, cd, 9,
                     264);
  hipLaunchKernelGGL(conv_mfma<false>, dim3(CGRID), dim3(256), 0, stream, bufB,
                     wHi + pd.dstOff[1], wLo + pd.dstOff[1], smpl_b + 0, bufC, cd, 8,
                     256);
  hipLaunchKernelGGL(conv_mfma<false>, dim3(CGRID), dim3(256), 0, stream, bufC,
                     wHi + pd.dstOff[2], wLo + pd.dstOff[2], smpl_b + 256, bufB, cd,
                     8, 256);
  hipLaunchKernelGGL(conv_mfma<false>, dim3(CGRID), dim3(256), 0, stream, bufB,
                     wHi + pd.dstOff[3], wLo + pd.dstOff[3], smpl_b + 512, bufC, cd,
                     8, 256);
  hipLaunchKernelGGL(head1x1, dim3(NT, 3), dim3(256), 0, stream, bufC, smpl_head_w,
                     smpl_head_b, smpl_init, out, hd);
  // ---- cate tower ----
  hipLaunchKernelGGL(conv_mfma<false>, dim3(CGRID), dim3(256), 0, stream, bufA,
                     wHi + pd.dstOff[4], wLo + pd.dstOff[4], cate_b0, bufB, cd, 8,
                     256);
  hipLaunchKernelGGL(conv_mfma<false>, dim3(CGRID), dim3(256), 0, stream, bufB,
                     wHi + pd.dstOff[5], wLo + pd.dstOff[5], cate_b + 0, bufC, cd, 8,
                     256);
  hipLaunchKernelGGL(conv_mfma<false>, dim3(CGRID), dim3(256), 0, stream, bufC,
                     wHi + pd.dstOff[6], wLo + pd.dstOff[6], cate_b + 256, bufB, cd,
                     8, 256);
  hipLaunchKernelGGL(conv_mfma<false>, dim3(CGRID), dim3(256), 0, stream, bufB,
                     wHi + pd.dstOff[7], wLo + pd.dstOff[7], cate_b + 512, bufC, cd,
                     8, 256);
  hipLaunchKernelGGL(cate_head_all, dim3((P[0] + 31) / 32, 5), dim3(256), 0, stream,
                     bufC, cate_head_w, cate_head_b, heat, sd);
  hipLaunchKernelGGL(nms_all, dim3((P[0] + 255) / 256, 5), dim3(256), 0, stream, heat,
                     out, nd);
  (void)in_sizes;
  (void)n_in;
  (void)out_size;
  (void)ws_size;
}

// Round 5
// 607.761 us; speedup vs baseline: 27.1268x; 1.3081x over previous
//
#include <hip/hip_runtime.h>
#include <math.h>
#include <stdint.h>

#define NLEV 5
#define PPT 17616  // sum over levels of 4*(g+2)^2

typedef __attribute__((ext_vector_type(8))) __bf16 bf16x8;
typedef __attribute__((ext_vector_type(4))) float f32x4;
typedef unsigned int u32;
typedef unsigned short u16;

__device__ __forceinline__ u32 f2bf(float f) {
  u32 u = __builtin_bit_cast(u32, f);
  return (u + 0x7FFFu + ((u >> 16) & 1u)) >> 16;
}
__device__ __forceinline__ u32 packSplit(float v) {
  u32 hi = f2bf(v);
  float fhi = __builtin_bit_cast(float, hi << 16);
  u32 lo = f2bf(v - fhi);
  return hi | (lo << 16);
}
__device__ __forceinline__ float unpackSum(u32 w) {
  return __builtin_bit_cast(float, w << 16) +
         __builtin_bit_cast(float, w & 0xFFFF0000u);
}

// Activation layout: u32 element (hi|lo bf16 packed) at
//   [(c>>3)*PPT + halo_px]*8 + (c&7)

// ---------------------------------------------------------------------------
// Weight prep: fp32 [Cout][Cin][3][3] -> MFMA A-frag layout, hi/lo bf16 planes.
// ks = cb*9 + tap (cb-major). elem = ((((coT*KS+ks)*2+f)*2+wco)*64+lane)*8+j
// co = coT*64+wco*32+f*16+(lane&15); ci = cb*32+(lane>>4)*8+j
// ---------------------------------------------------------------------------
struct PrepDesc {
  const float* src[8];
  int Cin[8];
  int CB[8];
  int dstOff[8];
};

__global__ __launch_bounds__(256) void prep_weights(PrepDesc pd, u16* __restrict__ wHi,
                                                    u16* __restrict__ wLo) {
  int cfg = blockIdx.y;
  int CB = pd.CB[cfg];
  int KS = CB * 9;
  int total = KS * 8192;
  int didx = blockIdx.x * 256 + threadIdx.x;
  if (didx >= total) return;
  int j = didx & 7;
  int lane = (didx >> 3) & 63;
  int wco = (didx >> 9) & 1;
  int f = (didx >> 10) & 1;
  int rest = didx >> 11;
  int ks = rest % KS;
  int coT = rest / KS;
  int cb = ks / 9;
  int tap = ks - cb * 9;
  int ci = cb * 32 + ((lane >> 4) << 3) + j;
  int co = coT * 64 + wco * 32 + f * 16 + (lane & 15);
  int Cin = pd.Cin[cfg];
  float v = 0.f;
  if (ci < Cin) v = pd.src[cfg][((size_t)co * Cin + ci) * 9 + tap];
  u32 hi = f2bf(v);
  float fhi = __builtin_bit_cast(float, hi << 16);
  u32 lo = f2bf(v - fhi);
  wHi[pd.dstOff[cfg] + didx] = (u16)hi;
  wLo[pd.dstOff[cfg] + didx] = (u16)lo;
}

// ---------------------------------------------------------------------------
// build: resize (optionally fused double resize) + coord ramps -> halo acts
// ---------------------------------------------------------------------------
struct BuildDesc {
  const float* src[NLEV];
  int H[NLEV];
  int mid[NLEV];
  int P[NLEV];
  int g[NLEV];
  int padOff[NLEV];
};

__device__ __forceinline__ float bsample(const float* __restrict__ pl, int H, int W,
                                         float fy, float fx) {
  int y0 = (int)floorf(fy);
  int y1 = min(y0 + 1, H - 1);
  float wy = fy - (float)y0;
  int x0 = (int)floorf(fx);
  int x1 = min(x0 + 1, W - 1);
  float wx = fx - (float)x0;
  const float* r0 = pl + (size_t)y0 * W;
  const float* r1 = pl + (size_t)y1 * W;
  float top = r0[x0] * (1.f - wx) + r0[x1] * wx;
  float bot = r1[x0] * (1.f - wx) + r1[x1] * wx;
  return top * (1.f - wy) + bot * wy;
}

__global__ __launch_bounds__(256) void build_all(BuildDesc bd, u32* __restrict__ dst) {
  int l = blockIdx.y;
  int P = bd.P[l];
  int g = bd.g[l];
  int total = 258 * P;
  int idx = blockIdx.x * 256 + threadIdx.x;
  if (idx >= total) return;
  int c = idx / P;
  int p = idx - c * P;
  int gg = g * g;
  int b = p / gg;
  int pr = p - b * gg;
  int i = pr / g;
  int j = pr - i * g;
  float val;
  if (c >= 256) {
    int tt = (c == 256) ? j : i;
    val = -1.f + 2.f * (float)tt / (float)(g - 1);
  } else {
    int H = bd.H[l], W = bd.H[l];
    int mid = bd.mid[l];
    const float* pl = bd.src[l] + ((size_t)b * 256 + c) * H * W;
    if (!mid) {
      float fy = (float)i * (float)(H - 1) / (float)(g - 1);
      float fx = (float)j * (float)(W - 1) / (float)(g - 1);
      val = bsample(pl, H, W, fy, fx);
    } else {
      int midh = mid, midw = mid;
      float fym = (float)i * (float)(midh - 1) / (float)(g - 1);
      float fxm = (float)j * (float)(midw - 1) / (float)(g - 1);
      int y0 = (int)floorf(fym);
      int y1 = min(y0 + 1, midh - 1);
      float wy = fym - (float)y0;
      int x0 = (int)floorf(fxm);
      int x1 = min(x0 + 1, midw - 1);
      float wx = fxm - (float)x0;
      float sy0 = (float)y0 * (float)(H - 1) / (float)(midh - 1);
      float sy1 = (float)y1 * (float)(H - 1) / (float)(midh - 1);
      float sx0 = (float)x0 * (float)(W - 1) / (float)(midw - 1);
      float sx1 = (float)x1 * (float)(W - 1) / (float)(midw - 1);
      float v00 = bsample(pl, H, W, sy0, sx0);
      float v01 = bsample(pl, H, W, sy0, sx1);
      float v10 = bsample(pl, H, W, sy1, sx0);
      float v11 = bsample(pl, H, W, sy1, sx1);
      float top = v00 * (1.f - wx) + v01 * wx;
      float bot = v10 * (1.f - wx) + v11 * wx;
      val = top * (1.f - wy) + bot * wy;
    }
  }
  int gp2 = g + 2;
  int hpos = bd.padOff[l] + b * gp2 * gp2 + (i + 1) * gp2 + (j + 1);
  dst[((size_t)(c >> 3) * PPT + hpos) * 8 + (c & 7)] = packSplit(val);
}

// ---------------------------------------------------------------------------
// MFMA conv 3x3 v2: halo tile in LDS per 32-ch block; taps barrier-free.
// 64co x 64px per block, 4 waves. LDS: 4 granules x 2 subplanes x 240px x 4 u32.
// ---------------------------------------------------------------------------
struct ConvDesc {
  int tileStart[NLEV + 1];
  int padOff[NLEV];
  int g[NLEV];
};

#define HPX 240  // max halo window (<=222 needed)

__global__ __launch_bounds__(256) void conv_mfma(
    const u32* __restrict__ actIn, const u16* __restrict__ wHi,
    const u16* __restrict__ wLo, const float* __restrict__ bias,
    u32* __restrict__ actOut, ConvDesc d, int CB) {
  const int bid = blockIdx.x;
  const int xcd = bid & 7;
  const int i6 = bid >> 3;
  const int coT = i6 & 3;
  const int tile = xcd + (i6 >> 2) * 8;
  const int NT = d.tileStart[NLEV];
  if (tile >= NT) return;

  int l = 0;
#pragma unroll
  for (int i = 1; i < NLEV; i++)
    if (tile >= d.tileStart[i]) l = i;
  const int g = d.g[l];
  const int gp2 = g + 2;
  const int hp2 = gp2 * gp2;
  const int gg = g * g;
  const int padOff = d.padOff[l];
  const int t = threadIdx.x;
  const int lane = t & 63;
  const int wv = t >> 6;
  const int wco = wv & 1, wp = wv >> 1;
  const int KS = CB * 9;
  const int ptile = (tile - d.tileStart[l]) * 64;

  // halo positions
  int b0 = ptile / gg;
  int pr0 = ptile - b0 * gg;
  int y0p = pr0 / g;
  int x0p = pr0 - y0p * g;
  const int h0 = padOff + b0 * hp2 + (y0p + 1) * gp2 + (x0p + 1) - gp2 - 1;

  const int pF0 = ptile + wp * 32 + (lane & 15);
  int bF = pF0 / gg;
  int prF = pF0 - bF * gg;
  int yF = prF / g;
  int xF = prF - yF * g;
  const int hF0 = padOff + bF * hp2 + (yF + 1) * gp2 + (xF + 1);
  int pF1 = pF0 + 16;
  int bF1 = pF1 / gg;
  int prF1 = pF1 - bF1 * gg;
  int yF1 = prF1 / g;
  int xF1 = prF1 - yF1 * g;
  const int hF1 = padOff + bF1 * hp2 + (yF1 + 1) * gp2 + (xF1 + 1);

  const int kb = lane >> 4;
  const int base0 = (hF0 - h0) * 4 + kb * (2 * HPX * 4);
  const int base1 = (hF1 - h0) * 4 + kb * (2 * HPX * 4);

  __shared__ u32 halo[4 * 2 * HPX * 4];  // 30720 B

  const int sgr = t >> 6;  // staging granule 0..3
  const int spx = t & 63;

  f32x4 acc00 = {0.f, 0.f, 0.f, 0.f}, acc01 = {0.f, 0.f, 0.f, 0.f};
  f32x4 acc10 = {0.f, 0.f, 0.f, 0.f}, acc11 = {0.f, 0.f, 0.f, 0.f};

  const size_t wbase =
      (size_t)coT * KS * 2048 + (size_t)wco * 512 + (size_t)lane * 8;
  bf16x8 ah0 = *(const bf16x8*)(wHi + wbase);
  bf16x8 ah1 = *(const bf16x8*)(wHi + wbase + 1024);
  bf16x8 al0 = *(const bf16x8*)(wLo + wbase);
  bf16x8 al1 = *(const bf16x8*)(wLo + wbase + 1024);

  for (int cb = 0; cb < CB; ++cb) {
    __syncthreads();  // prior tap reads done before overwrite
    {
      int gr = cb * 4 + sgr;
      const u32* srcp = actIn + ((size_t)gr * PPT + h0 + spx) * 8;
#pragma unroll
      for (int i = 0; i < 4; i++) {
        int idx = i * 64 + spx;
        uint4 a = *(const uint4*)(srcp + (size_t)i * 512);
        uint4 b2 = *(const uint4*)(srcp + (size_t)i * 512 + 4);
        if (idx < HPX) {
          *(uint4*)(halo + sgr * (2 * HPX * 4) + idx * 4) = a;
          *(uint4*)(halo + sgr * (2 * HPX * 4) + HPX * 4 + idx * 4) = b2;
        }
      }
    }
    __syncthreads();

#pragma unroll
    for (int tap = 0; tap < 9; ++tap) {
      const int ks = cb * 9 + tap;
      // prefetch next A frags (hidden under MFMAs)
      bf16x8 ah0n, ah1n, al0n, al1n;
      const bool have = (ks + 1) < KS;
      if (have) {
        size_t wo = wbase + (size_t)(ks + 1) * 2048;
        ah0n = *(const bf16x8*)(wHi + wo);
        ah1n = *(const bf16x8*)(wHi + wo + 1024);
        al0n = *(const bf16x8*)(wLo + wo);
        al1n = *(const bf16x8*)(wLo + wo + 1024);
      }
      const int toff = (tap / 3 - 1) * gp2 + (tap % 3) - 1;
      const u32* hp0 = halo + base0 + toff * 4;
      uint4 q0 = *(const uint4*)hp0;
      uint4 q1 = *(const uint4*)(hp0 + HPX * 4);
      const u32* hp1 = halo + base1 + toff * 4;
      uint4 r0 = *(const uint4*)hp1;
      uint4 r1 = *(const uint4*)(hp1 + HPX * 4);

      bf16x8 bh0, bl0, bh1, bl1;
      {
        uint4 hq, lq;
        hq.x = __builtin_amdgcn_perm(q0.y, q0.x, 0x05040100u);
        hq.y = __builtin_amdgcn_perm(q0.w, q0.z, 0x05040100u);
        hq.z = __builtin_amdgcn_perm(q1.y, q1.x, 0x05040100u);
        hq.w = __builtin_amdgcn_perm(q1.w, q1.z, 0x05040100u);
        lq.x = __builtin_amdgcn_perm(q0.y, q0.x, 0x07060302u);
        lq.y = __builtin_amdgcn_perm(q0.w, q0.z, 0x07060302u);
        lq.z = __builtin_amdgcn_perm(q1.y, q1.x, 0x07060302u);
        lq.w = __builtin_amdgcn_perm(q1.w, q1.z, 0x07060302u);
        bh0 = __builtin_bit_cast(bf16x8, hq);
        bl0 = __builtin_bit_cast(bf16x8, lq);
        hq.x = __builtin_amdgcn_perm(r0.y, r0.x, 0x05040100u);
        hq.y = __builtin_amdgcn_perm(r0.w, r0.z, 0x05040100u);
        hq.z = __builtin_amdgcn_perm(r1.y, r1.x, 0x05040100u);
        hq.w = __builtin_amdgcn_perm(r1.w, r1.z, 0x05040100u);
        lq.x = __builtin_amdgcn_perm(r0.y, r0.x, 0x07060302u);
        lq.y = __builtin_amdgcn_perm(r0.w, r0.z, 0x07060302u);
        lq.z = __builtin_amdgcn_perm(r1.y, r1.x, 0x07060302u);
        lq.w = __builtin_amdgcn_perm(r1.w, r1.z, 0x07060302u);
        bh1 = __builtin_bit_cast(bf16x8, hq);
        bl1 = __builtin_bit_cast(bf16x8, lq);
      }

      acc00 = __builtin_amdgcn_mfma_f32_16x16x32_bf16(ah0, bh0, acc00, 0, 0, 0);
      acc00 = __builtin_amdgcn_mfma_f32_16x16x32_bf16(ah0, bl0, acc00, 0, 0, 0);
      acc00 = __builtin_amdgcn_mfma_f32_16x16x32_bf16(al0, bh0, acc00, 0, 0, 0);
      acc01 = __builtin_amdgcn_mfma_f32_16x16x32_bf16(ah0, bh1, acc01, 0, 0, 0);
      acc01 = __builtin_amdgcn_mfma_f32_16x16x32_bf16(ah0, bl1, acc01, 0, 0, 0);
      acc01 = __builtin_amdgcn_mfma_f32_16x16x32_bf16(al0, bh1, acc01, 0, 0, 0);
      acc10 = __builtin_amdgcn_mfma_f32_16x16x32_bf16(ah1, bh0, acc10, 0, 0, 0);
      acc10 = __builtin_amdgcn_mfma_f32_16x16x32_bf16(ah1, bl0, acc10, 0, 0, 0);
      acc10 = __builtin_amdgcn_mfma_f32_16x16x32_bf16(al1, bh0, acc10, 0, 0, 0);
      acc11 = __builtin_amdgcn_mfma_f32_16x16x32_bf16(ah1, bh1, acc11, 0, 0, 0);
      acc11 = __builtin_amdgcn_mfma_f32_16x16x32_bf16(ah1, bl1, acc11, 0, 0, 0);
      acc11 = __builtin_amdgcn_mfma_f32_16x16x32_bf16(al1, bh1, acc11, 0, 0, 0);
      if (have) {
        ah0 = ah0n;
        ah1 = ah1n;
        al0 = al0n;
        al1 = al1n;
      }
    }
  }

  // epilogue: bias + relu + split-pack + granule halo store (dwordx4)
  int obase[2];
#pragma unroll
  for (int fp = 0; fp < 2; ++fp) {
    int po = ptile + wp * 32 + fp * 16 + (lane & 15);
    int bb = po / gg;
    int prr = po - bb * gg;
    int yy = prr / g;
    int xx = prr - yy * g;
    obase[fp] = padOff + bb * hp2 + (yy + 1) * gp2 + (xx + 1);
  }
  const int coBase = coT * 64 + wco * 32 + ((lane >> 4) << 2);
  float4 bA = *(const float4*)(bias + coBase);
  float4 bB = *(const float4*)(bias + coBase + 16);
  const size_t rowA = (size_t)(coBase >> 3) * PPT;
  const size_t rowB = (size_t)((coBase + 16) >> 3) * PPT;
  const int sub = coBase & 7;
  uint4 s;
  s.x = packSplit(fmaxf(acc00[0] + bA.x, 0.f));
  s.y = packSplit(fmaxf(acc00[1] + bA.y, 0.f));
  s.z = packSplit(fmaxf(acc00[2] + bA.z, 0.f));
  s.w = packSplit(fmaxf(acc00[3] + bA.w, 0.f));
  *(uint4*)(actOut + (rowA + obase[0]) * 8 + sub) = s;
  s.x = packSplit(fmaxf(acc01[0] + bA.x, 0.f));
  s.y = packSplit(fmaxf(acc01[1] + bA.y, 0.f));
  s.z = packSplit(fmaxf(acc01[2] + bA.z, 0.f));
  s.w = packSplit(fmaxf(acc01[3] + bA.w, 0.f));
  *(uint4*)(actOut + (rowA + obase[1]) * 8 + sub) = s;
  s.x = packSplit(fmaxf(acc10[0] + bB.x, 0.f));
  s.y = packSplit(fmaxf(acc10[1] + bB.y, 0.f));
  s.z = packSplit(fmaxf(acc10[2] + bB.z, 0.f));
  s.w = packSplit(fmaxf(acc10[3] + bB.w, 0.f));
  *(uint4*)(actOut + (rowB + obase[0]) * 8 + sub) = s;
  s.x = packSplit(fmaxf(acc11[0] + bB.x, 0.f));
  s.y = packSplit(fmaxf(acc11[1] + bB.y, 0.f));
  s.z = packSplit(fmaxf(acc11[2] + bB.z, 0.f));
  s.w = packSplit(fmaxf(acc11[3] + bB.w, 0.f));
  *(uint4*)(actOut + (rowB + obase[1]) * 8 + sub) = s;
}

// ---------------------------------------------------------------------------
// smpl head: 1x1 conv, Cout=157, +bias+init, NHWC out. scalar fp32.
// ---------------------------------------------------------------------------
struct HeadDesc {
  int tileStart[NLEV + 1];
  int padOff[NLEV];
  int g[NLEV];
  int outOff[NLEV];
};

__global__ __launch_bounds__(256) void head1x1(
    const u32* __restrict__ actIn, const float* __restrict__ w,
    const float* __restrict__ bias, const float* __restrict__ bias2,
    float* __restrict__ outB, HeadDesc d) {
  int bx = blockIdx.x;
  int l = 0;
#pragma unroll
  for (int i = 1; i < NLEV; i++)
    if (bx >= d.tileStart[i]) l = i;
  const int g = d.g[l];
  const int gp2 = g + 2, hp2 = gp2 * gp2, gg = g * g;
  const int t = threadIdx.x;
  const int ptile = (bx - d.tileStart[l]) * 64;
  const int pp = t & 63;
  int p = ptile + pp;
  int b = p / gg, pr = p - b * gg, y = pr / g, x = pr - y * g;
  const int hbase = d.padOff[l] + b * hp2 + (y + 1) * gp2 + (x + 1);
  const int co_tile = blockIdx.y * 64;
  __shared__ float As[32][68];
  __shared__ float Bs[32][68];
  const int tx = t & 15, ty = t >> 4;
  const int akk = t & 31, aco = t >> 5;
  const int kg = t >> 6;
  float acc[4][4];
#pragma unroll
  for (int i = 0; i < 4; i++)
#pragma unroll
    for (int j = 0; j < 4; j++) acc[i][j] = 0.f;

  for (int k0 = 0; k0 < 256; k0 += 32) {
#pragma unroll
    for (int i = 0; i < 8; i++) {
      int co = i * 8 + aco;
      int coG = co_tile + co;
      As[akk][co] = (coG < 157) ? w[(size_t)coG * 256 + k0 + akk] : 0.f;
    }
    {
      const u32* src = actIn + (((size_t)(k0 >> 3) + kg) * PPT + hbase) * 8;
#pragma unroll
      for (int j = 0; j < 8; j++) Bs[kg * 8 + j][pp] = unpackSum(src[j]);
    }
    __syncthreads();
#pragma unroll
    for (int kk = 0; kk < 32; kk++) {
      float4 a4 = *reinterpret_cast<const float4*>(&As[kk][ty * 4]);
      float4 b4 = *reinterpret_cast<const float4*>(&Bs[kk][tx * 4]);
      float av[4] = {a4.x, a4.y, a4.z, a4.w};
      float bv[4] = {b4.x, b4.y, b4.z, b4.w};
#pragma unroll
      for (int i = 0; i < 4; i++)
#pragma unroll
        for (int j = 0; j < 4; j++) acc[i][j] = fmaf(av[i], bv[j], acc[i][j]);
    }
    __syncthreads();
  }
  const int co0 = co_tile + ty * 4;
#pragma unroll
  for (int i = 0; i < 4; i++) {
    int co = co0 + i;
    if (co < 157) {
      float bb = bias[co] + bias2[co];
#pragma unroll
      for (int j = 0; j < 4; j++) {
        int pg = ptile + tx * 4 + j;
        outB[d.outOff[l] + (size_t)pg * 157 + co] = acc[i][j] + bb;
      }
    }
  }
}

// ---------------------------------------------------------------------------
// cate head v2: coalesced granule reads. thread=pixel, 4 waves split granules.
// ---------------------------------------------------------------------------
struct CHDesc {
  int tileStart[NLEV + 1];
  int padOff[NLEV];
  int g[NLEV];
  int outOff[NLEV];
};

__global__ __launch_bounds__(256) void cate_head_all(
    const u32* __restrict__ actIn, const float* __restrict__ w,
    const float* __restrict__ bias, float* __restrict__ heat, CHDesc d) {
  int tile = blockIdx.x;
  int l = 0;
#pragma unroll
  for (int i = 1; i < NLEV; i++)
    if (tile >= d.tileStart[i]) l = i;
  const int g = d.g[l];
  const int gp2 = g + 2, hp2 = gp2 * gp2, gg = g * g;
  const int t = threadIdx.x;
  const int ps = t & 63;
  const int cw = t >> 6;
  const int ptile = (tile - d.tileStart[l]) * 64;
  int p = ptile + ps;
  int b = p / gg, pr = p - b * gg, y = pr / g, x = pr - y * g;
  const int hbase = d.padOff[l] + b * hp2 + (y + 1) * gp2 + (x + 1);

  __shared__ float ws[32][9][8];  // [granule][tap][8ch]
  for (int i = t; i < 2304; i += 256) {
    int ci = i / 9, tap = i - ci * 9;
    ws[ci >> 3][tap][ci & 7] = w[i];
  }
  __syncthreads();

  float s = 0.f;
  for (int gr = cw; gr < 32; gr += 4) {
    const u32* bp = actIn + ((size_t)gr * PPT + hbase) * 8;
#pragma unroll
    for (int tap = 0; tap < 9; tap++) {
      const int toff = (tap / 3 - 1) * gp2 + (tap % 3) - 1;
      uint4 q0 = *(const uint4*)(bp + (ptrdiff_t)toff * 8);
      uint4 q1 = *(const uint4*)(bp + (ptrdiff_t)toff * 8 + 4);
      const float* wp = ws[gr][tap];
      s += unpackSum(q0.x) * wp[0] + unpackSum(q0.y) * wp[1] +
           unpackSum(q0.z) * wp[2] + unpackSum(q0.w) * wp[3] +
           unpackSum(q1.x) * wp[4] + unpackSum(q1.y) * wp[5] +
           unpackSum(q1.z) * wp[6] + unpackSum(q1.w) * wp[7];
    }
  }
  __shared__ float red[4][64];
  red[cw][ps] = s;
  __syncthreads();
  if (cw == 0) {
    float tot = bias[0] + red[0][ps] + red[1][ps] + red[2][ps] + red[3][ps];
    heat[d.outOff[l] + p] = 1.f / (1.f + expf(-tot));
  }
}

// points_nms * heat, flat heat in (cumP offsets), NHWC (C=1) out.
struct SmallDesc {
  int P[NLEV];
  int g[NLEV];
  int inOff[NLEV];
  int outOff[NLEV];
};

__global__ void nms_all(const float* __restrict__ heat, float* __restrict__ out,
                        SmallDesc d) {
  int l = blockIdx.y;
  int P = d.P[l], g = d.g[l];
  int gg = g * g;
  int p = blockIdx.x * 256 + threadIdx.x;
  if (p >= P) return;
  int pr = p % gg;
  int y = pr / g;
  int x = pr - y * g;
  const float* hb = heat + d.inOff[l];
  float c = hb[p], m = c;
  if (y > 0) {
    m = fmaxf(m, hb[p - g]);
    if (x > 0) m = fmaxf(m, hb[p - g - 1]);
  }
  if (x > 0) m = fmaxf(m, hb[p - 1]);
  out[d.outOff[l] + p] = (m == c) ? c : 0.f;
}

// ---------------------------------------------------------------------------
extern "C" void kernel_launch(void* const* d_in, const int* in_sizes, int n_in,
                              void* d_out, int out_size, void* d_ws, size_t ws_size,
                              hipStream_t stream) {
  const float* feat[5];
  for (int i = 0; i < 5; i++) feat[i] = (const float*)d_in[i];
  const float* smpl_w0 = (const float*)d_in[5];
  const float* smpl_b0 = (const float*)d_in[6];
  const float* smpl_w = (const float*)d_in[7];
  const float* smpl_b = (const float*)d_in[8];
  const float* cate_w0 = (const float*)d_in[9];
  const float* cate_b0 = (const float*)d_in[10];
  const float* cate_w = (const float*)d_in[11];
  const float* cate_b = (const float*)d_in[12];
  const float* cate_head_w = (const float*)d_in[13];
  const float* cate_head_b = (const float*)d_in[14];
  const float* smpl_head_w = (const float*)d_in[15];
  const float* smpl_head_b = (const float*)d_in[16];
  const float* smpl_init = (const float*)d_in[17];
  float* out = (float*)d_out;

  static const int GR[5] = {40, 36, 24, 16, 12};
  static const int SH[5] = {200, 100, 50, 25, 13};
  static const int MIDW[5] = {100, 0, 0, 0, 25};

  int P[5], cumP[6], tS[6], padOff[5];
  cumP[0] = 0;
  tS[0] = 0;
  int po = 0;
  for (int l = 0; l < 5; l++) {
    P[l] = 4 * GR[l] * GR[l];
    cumP[l + 1] = cumP[l] + P[l];
    tS[l + 1] = tS[l] + P[l] / 64;
    padOff[l] = po;
    po += 4 * (GR[l] + 2) * (GR[l] + 2);
  }

  int smpl_off[5], cate_off[5];
  {
    int off = 0;
    for (int l = 0; l < 5; l++) {
      smpl_off[l] = off;
      off += P[l] * 157;
    }
    for (int l = 0; l < 5; l++) {
      cate_off[l] = off;
      off += P[l];
    }
  }

  // workspace layout (u32 units): bufA 33 granule-rows, bufB/C 32 each
  u32* bufA = (u32*)d_ws;
  u32* bufB = bufA + (size_t)33 * PPT * 8;
  u32* bufC = bufB + (size_t)32 * PPT * 8;
  float* heat = (float*)(bufC + (size_t)32 * PPT * 8);
  const size_t WTOT = (size_t)(81 + 7 * 72) * 8192;
  u16* wHi = (u16*)(heat + 15488);
  u16* wLo = wHi + WTOT;
  const size_t ACT_BYTES = (size_t)(33 + 32 + 32) * PPT * 8 * 4 + 15488 * 4;

  hipMemsetAsync(d_ws, 0, ACT_BYTES, stream);

  // weight prep
  PrepDesc pd;
  const size_t LSTR = (size_t)256 * 256 * 9;
  pd.src[0] = smpl_w0;  pd.Cin[0] = 258;  pd.CB[0] = 9;
  pd.src[1] = smpl_w;   pd.Cin[1] = 256;  pd.CB[1] = 8;
  pd.src[2] = smpl_w + LSTR;     pd.Cin[2] = 256; pd.CB[2] = 8;
  pd.src[3] = smpl_w + 2 * LSTR; pd.Cin[3] = 256; pd.CB[3] = 8;
  pd.src[4] = cate_w0;  pd.Cin[4] = 256;  pd.CB[4] = 8;
  pd.src[5] = cate_w;   pd.Cin[5] = 256;  pd.CB[5] = 8;
  pd.src[6] = cate_w + LSTR;     pd.Cin[6] = 256; pd.CB[6] = 8;
  pd.src[7] = cate_w + 2 * LSTR; pd.Cin[7] = 256; pd.CB[7] = 8;
  {
    int off = 0;
    for (int i = 0; i < 8; i++) {
      pd.dstOff[i] = off;
      off += pd.CB[i] * 9 * 8192;
    }
  }
  hipLaunchKernelGGL(prep_weights, dim3(81 * 32, 8), dim3(256), 0, stream, pd, wHi,
                     wLo);

  // build inputs
  BuildDesc bd;
  for (int l = 0; l < 5; l++) {
    bd.src[l] = feat[l];
    bd.H[l] = SH[l];
    bd.mid[l] = MIDW[l];
    bd.P[l] = P[l];
    bd.g[l] = GR[l];
    bd.padOff[l] = padOff[l];
  }
  hipLaunchKernelGGL(build_all, dim3((258 * P[0] + 255) / 256, 5), dim3(256), 0,
                     stream, bd, bufA);

  ConvDesc cd;
  HeadDesc hd;
  CHDesc chd;
  SmallDesc nd;
  for (int i = 0; i <= 5; i++) {
    cd.tileStart[i] = tS[i];
    hd.tileStart[i] = tS[i];
    chd.tileStart[i] = tS[i];
  }
  for (int l = 0; l < 5; l++) {
    cd.padOff[l] = padOff[l];
    cd.g[l] = GR[l];
    hd.padOff[l] = padOff[l];
    hd.g[l] = GR[l];
    hd.outOff[l] = smpl_off[l];
    chd.padOff[l] = padOff[l];
    chd.g[l] = GR[l];
    chd.outOff[l] = cumP[l];
    nd.P[l] = P[l];
    nd.g[l] = GR[l];
    nd.inOff[l] = cumP[l];
    nd.outOff[l] = cate_off[l];
  }

  const int NT = tS[5];       // 242
  const int CGRID = 8 * 124;  // 992 blocks: 8 xcd slots x (31 tiles x 4 coT)
  // ---- smpl tower ----
  hipLaunchKernelGGL(conv_mfma, dim3(CGRID), dim3(256), 0, stream, bufA,
                     wHi + pd.dstOff[0], wLo + pd.dstOff[0], smpl_b0, bufB, cd, 9);
  hipLaunchKernelGGL(conv_mfma, dim3(CGRID), dim3(256), 0, stream, bufB,
                     wHi + pd.dstOff[1], wLo + pd.dstOff[1], smpl_b + 0, bufC, cd, 8);
  hipLaunchKernelGGL(conv_mfma, dim3(CGRID), dim3(256), 0, stream, bufC,
                     wHi + pd.dstOff[2], wLo + pd.dstOff[2], smpl_b + 256, bufB, cd,
                     8);
  hipLaunchKernelGGL(conv_mfma, dim3(CGRID), dim3(256), 0, stream, bufB,
                     wHi + pd.dstOff[3], wLo + pd.dstOff[3], smpl_b + 512, bufC, cd,
                     8);
  hipLaunchKernelGGL(head1x1, dim3(NT, 3), dim3(256), 0, stream, bufC, smpl_head_w,
                     smpl_head_b, smpl_init, out, hd);
  // ---- cate tower ----
  hipLaunchKernelGGL(conv_mfma, dim3(CGRID), dim3(256), 0, stream, bufA,
                     wHi + pd.dstOff[4], wLo + pd.dstOff[4], cate_b0, bufB, cd, 8);
  hipLaunchKernelGGL(conv_mfma, dim3(CGRID), dim3(256), 0, stream, bufB,
                     wHi + pd.dstOff[5], wLo + pd.dstOff[5], cate_b + 0, bufC, cd, 8);
  hipLaunchKernelGGL(conv_mfma, dim3(CGRID), dim3(256), 0, stream, bufC,
                     wHi + pd.dstOff[6], wLo + pd.dstOff[6], cate_b + 256, bufB, cd,
                     8);
  hipLaunchKernelGGL(conv_mfma, dim3(CGRID), dim3(256), 0, stream, bufB,
                     wHi + pd.dstOff[7], wLo + pd.dstOff[7], cate_b + 512, bufC, cd,
                     8);
  hipLaunchKernelGGL(cate_head_all, dim3(NT), dim3(256), 0, stream, bufC,
                     cate_head_w, cate_head_b, heat, chd);
  hipLaunchKernelGGL(nms_all, dim3((P[0] + 255) / 256, 5), dim3(256), 0, stream,
                     heat, out, nd);
  (void)in_sizes;
  (void)n_in;
  (void)out_size;
  (void)ws_size;
}

// Round 6
// 528.517 us; speedup vs baseline: 31.1941x; 1.1499x over previous
//
#include <hip/hip_runtime.h>
#include <math.h>
#include <stdint.h>

#define NLEV 5
#define PPT 17616  // sum over levels of 4*(g+2)^2
#define HPX 320    // staged halo window (max needed span = 306)

typedef __attribute__((ext_vector_type(8))) __bf16 bf16x8;
typedef __attribute__((ext_vector_type(4))) float f32x4;
typedef unsigned int u32;
typedef unsigned short u16;

#define MFMA16 __builtin_amdgcn_mfma_f32_16x16x32_bf16

__device__ __forceinline__ u32 f2bf(float f) {
  u32 u = __builtin_bit_cast(u32, f);
  return (u + 0x7FFFu + ((u >> 16) & 1u)) >> 16;
}
__device__ __forceinline__ u32 packSplit(float v) {
  u32 hi = f2bf(v);
  float fhi = __builtin_bit_cast(float, hi << 16);
  u32 lo = f2bf(v - fhi);
  return hi | (lo << 16);
}
__device__ __forceinline__ float unpackSum(u32 w) {
  return __builtin_bit_cast(float, w << 16) +
         __builtin_bit_cast(float, w & 0xFFFF0000u);
}
// split 8 packed hi|lo u32 (2 uint4) into hi-plane / lo-plane uint4s of bf16 pairs
__device__ __forceinline__ void splitPerm(const uint4& a, const uint4& b, uint4& hq,
                                          uint4& lq) {
  hq.x = __builtin_amdgcn_perm(a.y, a.x, 0x05040100u);
  hq.y = __builtin_amdgcn_perm(a.w, a.z, 0x05040100u);
  hq.z = __builtin_amdgcn_perm(b.y, b.x, 0x05040100u);
  hq.w = __builtin_amdgcn_perm(b.w, b.z, 0x05040100u);
  lq.x = __builtin_amdgcn_perm(a.y, a.x, 0x07060302u);
  lq.y = __builtin_amdgcn_perm(a.w, a.z, 0x07060302u);
  lq.z = __builtin_amdgcn_perm(b.y, b.x, 0x07060302u);
  lq.w = __builtin_amdgcn_perm(b.w, b.z, 0x07060302u);
}

// Activation layout: u32 element (hi|lo bf16 packed) at
//   [(c>>3)*PPT + halo_px]*8 + (c&7)

// ---------------------------------------------------------------------------
// Weight prep: fp32 [Cout][Cin][TAPS] -> MFMA A-frag layout, hi/lo planes.
// ks = cb*TAPS + tap. elem = ((((coT*KS+ks)*2+f)*2+wco)*64+lane)*8+j
// co = coT*64+wco*32+f*16+(lane&15); ci = cb*32+(lane>>4)*8+j
// ---------------------------------------------------------------------------
struct PrepDesc {
  const float* src[9];
  int Cin[9];
  int Cout[9];
  int CB[9];
  int TAPS[9];
  int nCoT[9];
  int dstOff[9];
};

__global__ __launch_bounds__(256) void prep_weights(PrepDesc pd, u16* __restrict__ wHi,
                                                    u16* __restrict__ wLo) {
  int cfg = blockIdx.y;
  int CB = pd.CB[cfg];
  int TAPS = pd.TAPS[cfg];
  int KS = CB * TAPS;
  int total = KS * 2048 * pd.nCoT[cfg];
  int didx = blockIdx.x * 256 + threadIdx.x;
  if (didx >= total) return;
  int j = didx & 7;
  int lane = (didx >> 3) & 63;
  int wco = (didx >> 9) & 1;
  int f = (didx >> 10) & 1;
  int rest = didx >> 11;
  int ks = rest % KS;
  int coT = rest / KS;
  int cb = ks / TAPS;
  int tap = ks - cb * TAPS;
  int ci = cb * 32 + ((lane >> 4) << 3) + j;
  int co = coT * 64 + wco * 32 + f * 16 + (lane & 15);
  float v = 0.f;
  if (ci < pd.Cin[cfg] && co < pd.Cout[cfg])
    v = pd.src[cfg][((size_t)co * pd.Cin[cfg] + ci) * TAPS + tap];
  u32 hi = f2bf(v);
  float fhi = __builtin_bit_cast(float, hi << 16);
  u32 lo = f2bf(v - fhi);
  wHi[pd.dstOff[cfg] + didx] = (u16)hi;
  wLo[pd.dstOff[cfg] + didx] = (u16)lo;
}

// ---------------------------------------------------------------------------
// halo ring zero for the 4 tower buffers (128 granule-rows from base)
// ---------------------------------------------------------------------------
struct ZeroDesc {
  int padOff[NLEV];
  int g[NLEV];
};

__global__ __launch_bounds__(256) void halo_zero(u32* __restrict__ base, ZeroDesc zd) {
  int px = blockIdx.x * 256 + threadIdx.x;
  if (px >= PPT) return;
  int l = 0;
#pragma unroll
  for (int i = 1; i < NLEV; i++)
    if (px >= zd.padOff[i]) l = i;
  int g = zd.g[l], gp2 = g + 2, hp2 = gp2 * gp2;
  int local = px - zd.padOff[l];
  int b = local / hp2;
  int rem = local - b * hp2;
  int yy = rem / gp2, xx = rem - yy * gp2;
  if (yy >= 1 && yy <= g && xx >= 1 && xx <= g) return;  // interior
  int r = blockIdx.y;
  uint4 z = {0u, 0u, 0u, 0u};
  u32* p = base + ((size_t)r * PPT + px) * 8;
  *(uint4*)p = z;
  *(uint4*)(p + 4) = z;
}

// ---------------------------------------------------------------------------
// build: resize (optionally fused double resize) + coord ramps -> halo acts
// ---------------------------------------------------------------------------
struct BuildDesc {
  const float* src[NLEV];
  int H[NLEV];
  int mid[NLEV];
  int P[NLEV];
  int g[NLEV];
  int padOff[NLEV];
};

__device__ __forceinline__ float bsample(const float* __restrict__ pl, int H, int W,
                                         float fy, float fx) {
  int y0 = (int)floorf(fy);
  int y1 = min(y0 + 1, H - 1);
  float wy = fy - (float)y0;
  int x0 = (int)floorf(fx);
  int x1 = min(x0 + 1, W - 1);
  float wx = fx - (float)x0;
  const float* r0 = pl + (size_t)y0 * W;
  const float* r1 = pl + (size_t)y1 * W;
  float top = r0[x0] * (1.f - wx) + r0[x1] * wx;
  float bot = r1[x0] * (1.f - wx) + r1[x1] * wx;
  return top * (1.f - wy) + bot * wy;
}

__global__ __launch_bounds__(256) void build_all(BuildDesc bd, u32* __restrict__ dst) {
  int l = blockIdx.y;
  int P = bd.P[l];
  int g = bd.g[l];
  int total = 258 * P;
  int idx = blockIdx.x * 256 + threadIdx.x;
  if (idx >= total) return;
  int c = idx / P;
  int p = idx - c * P;
  int gg = g * g;
  int b = p / gg;
  int pr = p - b * gg;
  int i = pr / g;
  int j = pr - i * g;
  float val;
  if (c >= 256) {
    int tt = (c == 256) ? j : i;
    val = -1.f + 2.f * (float)tt / (float)(g - 1);
  } else {
    int H = bd.H[l], W = bd.H[l];
    int mid = bd.mid[l];
    const float* pl = bd.src[l] + ((size_t)b * 256 + c) * H * W;
    if (!mid) {
      float fy = (float)i * (float)(H - 1) / (float)(g - 1);
      float fx = (float)j * (float)(W - 1) / (float)(g - 1);
      val = bsample(pl, H, W, fy, fx);
    } else {
      int midh = mid, midw = mid;
      float fym = (float)i * (float)(midh - 1) / (float)(g - 1);
      float fxm = (float)j * (float)(midw - 1) / (float)(g - 1);
      int y0 = (int)floorf(fym);
      int y1 = min(y0 + 1, midh - 1);
      float wy = fym - (float)y0;
      int x0 = (int)floorf(fxm);
      int x1 = min(x0 + 1, midw - 1);
      float wx = fxm - (float)x0;
      float sy0 = (float)y0 * (float)(H - 1) / (float)(midh - 1);
      float sy1 = (float)y1 * (float)(H - 1) / (float)(midh - 1);
      float sx0 = (float)x0 * (float)(W - 1) / (float)(midw - 1);
      float sx1 = (float)x1 * (float)(W - 1) / (float)(midw - 1);
      float v00 = bsample(pl, H, W, sy0, sx0);
      float v01 = bsample(pl, H, W, sy0, sx1);
      float v10 = bsample(pl, H, W, sy1, sx0);
      float v11 = bsample(pl, H, W, sy1, sx1);
      float top = v00 * (1.f - wx) + v01 * wx;
      float bot = v10 * (1.f - wx) + v11 * wx;
      val = top * (1.f - wy) + bot * wy;
    }
  }
  int gp2 = g + 2;
  int hpos = bd.padOff[l] + b * gp2 * gp2 + (i + 1) * gp2 + (j + 1);
  dst[((size_t)(c >> 3) * PPT + hpos) * 8 + (c & 7)] = packSplit(val);
}

// ---------------------------------------------------------------------------
// MFMA conv 3x3 v3: merged towers, 128px x 64co tiles, pre-split LDS planes.
// 4 waves (2co x 2px-half); each wave: 2 co-frags x 4 px-frags, 24 MFMA/tap.
// ---------------------------------------------------------------------------
struct ConvDesc {
  int tS[NLEV + 1];  // cumulative 128-px tiles: 0,50,91,109,117,122
  int padOff[NLEV];
  int g[NLEV];
  int P[NLEV];
};

__global__ __launch_bounds__(256) void conv_mfma(
    const u32* __restrict__ inS, const u32* __restrict__ inC,
    const u16* __restrict__ wHiB, const u16* __restrict__ wLoB, int wOffS,
    int wOffC, const float* __restrict__ bS, const float* __restrict__ bC,
    u32* __restrict__ outS, u32* __restrict__ outC, ConvDesc d, int CBS, int CBC) {
  const int bid = blockIdx.x;
  const int xcd = bid & 7;
  const int i6 = bid >> 3;         // 0..127
  const int tower = i6 & 1;
  const int coT = (i6 >> 1) & 3;
  const int tile = xcd + (i6 >> 3) * 8;
  if (tile >= d.tS[NLEV]) return;

  const u32* __restrict__ actIn = tower ? inC : inS;
  u32* __restrict__ actOut = tower ? outC : outS;
  const u16* __restrict__ wH = wHiB + (tower ? wOffC : wOffS);
  const u16* __restrict__ wL = wLoB + (tower ? wOffC : wOffS);
  const float* __restrict__ bias = tower ? bC : bS;
  const int CB = tower ? CBC : CBS;
  const int KS = CB * 9;

  int l = 0;
#pragma unroll
  for (int i = 1; i < NLEV; i++)
    if (tile >= d.tS[i]) l = i;
  const int g = d.g[l];
  const int gp2 = g + 2, hp2 = gp2 * gp2, gg = g * g;
  const int padOff = d.padOff[l];
  const int Pl = d.P[l];
  const int ptile = (tile - d.tS[l]) * 128;

  const int t = threadIdx.x;
  const int lane = t & 63;
  const int wv = t >> 6;
  const int wco = wv & 1, wp = wv >> 1;
  const int kb = lane >> 4;
  const int sgr = wv;   // staging granule index
  const int spx = lane;

  int h0;
  {
    int b0 = ptile / gg, pr0 = ptile - b0 * gg;
    int y0 = pr0 / g, x0 = pr0 - y0 * g;
    h0 = padOff + b0 * hp2 + (y0 + 1) * gp2 + (x0 + 1) - gp2 - 1;
  }

  int hRel[4], ob[4];
  bool vst[4];
#pragma unroll
  for (int fi = 0; fi < 4; fi++) {
    int pb = ptile + wp * 64 + fi * 16;
    vst[fi] = pb < Pl;
    int pf = pb + (lane & 15);
    if (pf >= Pl) pf = Pl - 1;
    int b = pf / gg, pr = pf - b * gg;
    int y = pr / g, x = pr - y * g;
    int h = padOff + b * hp2 + (y + 1) * gp2 + (x + 1);
    hRel[fi] = h - h0;
    ob[fi] = h;
  }

  __shared__ u32 halo[4 * 2 * HPX * 4];  // 40960 B: [gr][plane][px][4]

  f32x4 acc[2][4];
#pragma unroll
  for (int c = 0; c < 2; c++)
#pragma unroll
    for (int fi = 0; fi < 4; fi++) acc[c][fi] = (f32x4){0.f, 0.f, 0.f, 0.f};

  const size_t wbase =
      (size_t)coT * KS * 2048 + (size_t)wco * 512 + (size_t)lane * 8;
  bf16x8 ah0 = *(const bf16x8*)(wH + wbase);
  bf16x8 ah1 = *(const bf16x8*)(wH + wbase + 1024);
  bf16x8 al0 = *(const bf16x8*)(wL + wbase);
  bf16x8 al1 = *(const bf16x8*)(wL + wbase + 1024);

  for (int cb = 0; cb < CB; ++cb) {
    __syncthreads();  // prior tap reads done before overwrite
    {
      const int gr = cb * 4 + sgr;
      const u32* srcp = actIn + ((size_t)gr * PPT + h0) * 8;
      u32* dhi = halo + sgr * (2 * HPX * 4);
      u32* dlo = dhi + HPX * 4;
#pragma unroll
      for (int i = 0; i < 5; i++) {
        int px = i * 64 + spx;
        uint4 a = *(const uint4*)(srcp + (size_t)px * 8);
        uint4 b2 = *(const uint4*)(srcp + (size_t)px * 8 + 4);
        uint4 hq, lq;
        splitPerm(a, b2, hq, lq);
        *(uint4*)(dhi + px * 4) = hq;
        *(uint4*)(dlo + px * 4) = lq;
      }
    }
    __syncthreads();

#pragma unroll
    for (int tap = 0; tap < 9; ++tap) {
      const int ks = cb * 9 + tap;
      bf16x8 ah0n, ah1n, al0n, al1n;
      const bool have = (ks + 1) < KS;
      if (have) {
        size_t wo = wbase + (size_t)(ks + 1) * 2048;
        ah0n = *(const bf16x8*)(wH + wo);
        ah1n = *(const bf16x8*)(wH + wo + 1024);
        al0n = *(const bf16x8*)(wL + wo);
        al1n = *(const bf16x8*)(wL + wo + 1024);
      }
      const int toff = (tap / 3 - 1) * gp2 + (tap % 3) - 1;
      const u32* kbase = halo + kb * (2 * HPX * 4);
#pragma unroll
      for (int fi = 0; fi < 4; fi++) {
        const u32* p0 = kbase + (hRel[fi] + toff) * 4;
        bf16x8 bh = __builtin_bit_cast(bf16x8, *(const uint4*)p0);
        bf16x8 bl = __builtin_bit_cast(bf16x8, *(const uint4*)(p0 + HPX * 4));
        acc[0][fi] = MFMA16(ah0, bh, acc[0][fi], 0, 0, 0);
        acc[0][fi] = MFMA16(ah0, bl, acc[0][fi], 0, 0, 0);
        acc[0][fi] = MFMA16(al0, bh, acc[0][fi], 0, 0, 0);
        acc[1][fi] = MFMA16(ah1, bh, acc[1][fi], 0, 0, 0);
        acc[1][fi] = MFMA16(ah1, bl, acc[1][fi], 0, 0, 0);
        acc[1][fi] = MFMA16(al1, bh, acc[1][fi], 0, 0, 0);
      }
      if (have) {
        ah0 = ah0n;
        ah1 = ah1n;
        al0 = al0n;
        al1 = al1n;
      }
    }
  }

  // epilogue: bias + relu + split-pack + granule halo store (dwordx4)
  const int coBase = coT * 64 + wco * 32 + ((lane >> 4) << 2);
  float4 bA = *(const float4*)(bias + coBase);
  float4 bB = *(const float4*)(bias + coBase + 16);
  const size_t rowA = (size_t)(coBase >> 3) * PPT;
  const size_t rowB = (size_t)((coBase + 16) >> 3) * PPT;
  const int sub = coBase & 7;
#pragma unroll
  for (int fi = 0; fi < 4; fi++) {
    if (!vst[fi]) continue;
    uint4 s;
    s.x = packSplit(fmaxf(acc[0][fi][0] + bA.x, 0.f));
    s.y = packSplit(fmaxf(acc[0][fi][1] + bA.y, 0.f));
    s.z = packSplit(fmaxf(acc[0][fi][2] + bA.z, 0.f));
    s.w = packSplit(fmaxf(acc[0][fi][3] + bA.w, 0.f));
    *(uint4*)(actOut + (rowA + ob[fi]) * 8 + sub) = s;
    s.x = packSplit(fmaxf(acc[1][fi][0] + bB.x, 0.f));
    s.y = packSplit(fmaxf(acc[1][fi][1] + bB.y, 0.f));
    s.z = packSplit(fmaxf(acc[1][fi][2] + bB.z, 0.f));
    s.w = packSplit(fmaxf(acc[1][fi][3] + bB.w, 0.f));
    *(uint4*)(actOut + (rowB + ob[fi]) * 8 + sub) = s;
  }
}

// ---------------------------------------------------------------------------
// smpl head: 1x1 conv via MFMA (K=256, Cout 157 padded to 192), NHWC out.
// ---------------------------------------------------------------------------
struct HeadDesc {
  int tS64[NLEV + 1];
  int padOff[NLEV];
  int g[NLEV];
  int outOff[NLEV];
};

__global__ __launch_bounds__(256) void head1x1(
    const u32* __restrict__ actIn, const u16* __restrict__ wH,
    const u16* __restrict__ wL, const float* __restrict__ bias,
    const float* __restrict__ bias2, float* __restrict__ outB, HeadDesc d) {
  const int bx = blockIdx.x;
  const int coT = blockIdx.y;
  int l = 0;
#pragma unroll
  for (int i = 1; i < NLEV; i++)
    if (bx >= d.tS64[i]) l = i;
  const int g = d.g[l], gp2 = g + 2, hp2 = gp2 * gp2, gg = g * g;
  const int ptile = (bx - d.tS64[l]) * 64;
  const int t = threadIdx.x, lane = t & 63, wv = t >> 6;
  const int wco = wv & 1, wp = wv >> 1, kb = lane >> 4;

  int hp[2], pF[2];
#pragma unroll
  for (int fi = 0; fi < 2; fi++) {
    int pf = ptile + wp * 32 + fi * 16 + (lane & 15);
    pF[fi] = pf;
    int b = pf / gg, pr = pf - b * gg, y = pr / g, x = pr - y * g;
    hp[fi] = d.padOff[l] + b * hp2 + (y + 1) * gp2 + (x + 1);
  }
  f32x4 acc[2][2];
#pragma unroll
  for (int c = 0; c < 2; c++)
#pragma unroll
    for (int fi = 0; fi < 2; fi++) acc[c][fi] = (f32x4){0.f, 0.f, 0.f, 0.f};

  const size_t wbase = (size_t)coT * 8 * 2048 + (size_t)wco * 512 + (size_t)lane * 8;
  for (int cb = 0; cb < 8; ++cb) {
    size_t wo = wbase + (size_t)cb * 2048;
    bf16x8 ah0 = *(const bf16x8*)(wH + wo);
    bf16x8 ah1 = *(const bf16x8*)(wH + wo + 1024);
    bf16x8 al0 = *(const bf16x8*)(wL + wo);
    bf16x8 al1 = *(const bf16x8*)(wL + wo + 1024);
    const int gr = cb * 4 + kb;
#pragma unroll
    for (int fi = 0; fi < 2; fi++) {
      const u32* bp = actIn + ((size_t)gr * PPT + hp[fi]) * 8;
      uint4 a = *(const uint4*)bp;
      uint4 b2 = *(const uint4*)(bp + 4);
      uint4 hq, lq;
      splitPerm(a, b2, hq, lq);
      bf16x8 bh = __builtin_bit_cast(bf16x8, hq);
      bf16x8 bl = __builtin_bit_cast(bf16x8, lq);
      acc[0][fi] = MFMA16(ah0, bh, acc[0][fi], 0, 0, 0);
      acc[0][fi] = MFMA16(ah0, bl, acc[0][fi], 0, 0, 0);
      acc[0][fi] = MFMA16(al0, bh, acc[0][fi], 0, 0, 0);
      acc[1][fi] = MFMA16(ah1, bh, acc[1][fi], 0, 0, 0);
      acc[1][fi] = MFMA16(ah1, bl, acc[1][fi], 0, 0, 0);
      acc[1][fi] = MFMA16(al1, bh, acc[1][fi], 0, 0, 0);
    }
  }
  const int coBase = coT * 64 + wco * 32 + ((lane >> 4) << 2);
#pragma unroll
  for (int c = 0; c < 2; c++)
#pragma unroll
    for (int fi = 0; fi < 2; fi++)
#pragma unroll
      for (int i = 0; i < 4; i++) {
        int co = coBase + c * 16 + i;
        if (co < 157)
          outB[d.outOff[l] + (size_t)pF[fi] * 157 + co] =
              acc[c][fi][i] + bias[co] + bias2[co];
      }
}

// ---------------------------------------------------------------------------
// cate head: 3x3 conv Cout=1 + sigmoid; coalesced granule reads.
// ---------------------------------------------------------------------------
struct CHDesc {
  int tS64[NLEV + 1];
  int padOff[NLEV];
  int g[NLEV];
  int outOff[NLEV];
};

__global__ __launch_bounds__(256) void cate_head_all(
    const u32* __restrict__ actIn, const float* __restrict__ w,
    const float* __restrict__ bias, float* __restrict__ heat, CHDesc d) {
  int tile = blockIdx.x;
  int l = 0;
#pragma unroll
  for (int i = 1; i < NLEV; i++)
    if (tile >= d.tS64[i]) l = i;
  const int g = d.g[l];
  const int gp2 = g + 2, hp2 = gp2 * gp2, gg = g * g;
  const int t = threadIdx.x;
  const int ps = t & 63;
  const int cw = t >> 6;
  const int ptile = (tile - d.tS64[l]) * 64;
  int p = ptile + ps;
  int b = p / gg, pr = p - b * gg, y = pr / g, x = pr - y * g;
  const int hbase = d.padOff[l] + b * hp2 + (y + 1) * gp2 + (x + 1);

  __shared__ float ws[32][9][8];
  for (int i = t; i < 2304; i += 256) {
    int ci = i / 9, tap = i - ci * 9;
    ws[ci >> 3][tap][ci & 7] = w[i];
  }
  __syncthreads();

  float s = 0.f;
  for (int gr = cw; gr < 32; gr += 4) {
    const u32* bp = actIn + ((size_t)gr * PPT + hbase) * 8;
#pragma unroll
    for (int tap = 0; tap < 9; tap++) {
      const int toff = (tap / 3 - 1) * gp2 + (tap % 3) - 1;
      uint4 q0 = *(const uint4*)(bp + (ptrdiff_t)toff * 8);
      uint4 q1 = *(const uint4*)(bp + (ptrdiff_t)toff * 8 + 4);
      const float* wp = ws[gr][tap];
      s += unpackSum(q0.x) * wp[0] + unpackSum(q0.y) * wp[1] +
           unpackSum(q0.z) * wp[2] + unpackSum(q0.w) * wp[3] +
           unpackSum(q1.x) * wp[4] + unpackSum(q1.y) * wp[5] +
           unpackSum(q1.z) * wp[6] + unpackSum(q1.w) * wp[7];
    }
  }
  __shared__ float red[4][64];
  red[cw][ps] = s;
  __syncthreads();
  if (cw == 0) {
    float tot = bias[0] + red[0][ps] + red[1][ps] + red[2][ps] + red[3][ps];
    heat[d.outOff[l] + p] = 1.f / (1.f + expf(-tot));
  }
}

// points_nms * heat, flat heat in (cumP offsets), NHWC (C=1) out.
struct SmallDesc {
  int P[NLEV];
  int g[NLEV];
  int inOff[NLEV];
  int outOff[NLEV];
};

__global__ void nms_all(const float* __restrict__ heat, float* __restrict__ out,
                        SmallDesc d) {
  int l = blockIdx.y;
  int P = d.P[l], g = d.g[l];
  int gg = g * g;
  int p = blockIdx.x * 256 + threadIdx.x;
  if (p >= P) return;
  int pr = p % gg;
  int y = pr / g;
  int x = pr - y * g;
  const float* hb = heat + d.inOff[l];
  float c = hb[p], m = c;
  if (y > 0) {
    m = fmaxf(m, hb[p - g]);
    if (x > 0) m = fmaxf(m, hb[p - g - 1]);
  }
  if (x > 0) m = fmaxf(m, hb[p - 1]);
  out[d.outOff[l] + p] = (m == c) ? c : 0.f;
}

// ---------------------------------------------------------------------------
extern "C" void kernel_launch(void* const* d_in, const int* in_sizes, int n_in,
                              void* d_out, int out_size, void* d_ws, size_t ws_size,
                              hipStream_t stream) {
  const float* feat[5];
  for (int i = 0; i < 5; i++) feat[i] = (const float*)d_in[i];
  const float* smpl_w0 = (const float*)d_in[5];
  const float* smpl_b0 = (const float*)d_in[6];
  const float* smpl_w = (const float*)d_in[7];
  const float* smpl_b = (const float*)d_in[8];
  const float* cate_w0 = (const float*)d_in[9];
  const float* cate_b0 = (const float*)d_in[10];
  const float* cate_w = (const float*)d_in[11];
  const float* cate_b = (const float*)d_in[12];
  const float* cate_head_w = (const float*)d_in[13];
  const float* cate_head_b = (const float*)d_in[14];
  const float* smpl_head_w = (const float*)d_in[15];
  const float* smpl_head_b = (const float*)d_in[16];
  const float* smpl_init = (const float*)d_in[17];
  float* out = (float*)d_out;

  static const int GR[5] = {40, 36, 24, 16, 12};
  static const int SH[5] = {200, 100, 50, 25, 13};
  static const int MIDW[5] = {100, 0, 0, 0, 25};

  int P[5], cumP[6], tS64[6], tS128[6], padOff[5];
  cumP[0] = 0;
  tS64[0] = 0;
  tS128[0] = 0;
  int po = 0;
  for (int l = 0; l < 5; l++) {
    P[l] = 4 * GR[l] * GR[l];
    cumP[l + 1] = cumP[l] + P[l];
    tS64[l + 1] = tS64[l] + P[l] / 64;
    tS128[l + 1] = tS128[l] + (P[l] + 127) / 128;
    padOff[l] = po;
    po += 4 * (GR[l] + 2) * (GR[l] + 2);
  }

  int smpl_off[5], cate_off[5];
  {
    int off = 0;
    for (int l = 0; l < 5; l++) {
      smpl_off[l] = off;
      off += P[l] * 157;
    }
    for (int l = 0; l < 5; l++) {
      cate_off[l] = off;
      off += P[l];
    }
  }

  // workspace: bufA(36 rows) | Bs | Cs | Bc | Cc (32 rows each) | heat | wHi | wLo
  u32* bufA = (u32*)d_ws;
  u32* bufBs = bufA + (size_t)36 * PPT * 8;
  u32* bufCs = bufBs + (size_t)32 * PPT * 8;
  u32* bufBc = bufCs + (size_t)32 * PPT * 8;
  u32* bufCc = bufBc + (size_t)32 * PPT * 8;
  float* heat = (float*)(bufCc + (size_t)32 * PPT * 8);
  u16* wHi = (u16*)(heat + 15488);

  // weight prep configs
  PrepDesc pd;
  const size_t LSTR = (size_t)256 * 256 * 9;
  pd.src[0] = smpl_w0;
  pd.src[1] = smpl_w;
  pd.src[2] = smpl_w + LSTR;
  pd.src[3] = smpl_w + 2 * LSTR;
  pd.src[4] = cate_w0;
  pd.src[5] = cate_w;
  pd.src[6] = cate_w + LSTR;
  pd.src[7] = cate_w + 2 * LSTR;
  pd.src[8] = smpl_head_w;
  for (int i = 0; i < 9; i++) {
    pd.Cin[i] = 256;
    pd.Cout[i] = 256;
    pd.CB[i] = 8;
    pd.TAPS[i] = 9;
    pd.nCoT[i] = 4;
  }
  pd.Cin[0] = 258;
  pd.CB[0] = 9;
  pd.Cout[8] = 157;
  pd.TAPS[8] = 1;
  pd.nCoT[8] = 3;
  size_t WTOT = 0;
  for (int i = 0; i < 9; i++) {
    pd.dstOff[i] = (int)WTOT;
    WTOT += (size_t)pd.CB[i] * pd.TAPS[i] * 2048 * pd.nCoT[i];
  }
  u16* wLo = wHi + WTOT;

  // zero bufA (incl. pad granules 33-35 + ring); ring-zero the 4 tower buffers
  hipMemsetAsync(bufA, 0, (size_t)36 * PPT * 32, stream);
  ZeroDesc zd;
  for (int l = 0; l < 5; l++) {
    zd.padOff[l] = padOff[l];
    zd.g[l] = GR[l];
  }
  hipLaunchKernelGGL(halo_zero, dim3((PPT + 255) / 256, 128), dim3(256), 0, stream,
                     bufBs, zd);

  hipLaunchKernelGGL(prep_weights, dim3(2592, 9), dim3(256), 0, stream, pd, wHi, wLo);

  // build inputs
  BuildDesc bd;
  for (int l = 0; l < 5; l++) {
    bd.src[l] = feat[l];
    bd.H[l] = SH[l];
    bd.mid[l] = MIDW[l];
    bd.P[l] = P[l];
    bd.g[l] = GR[l];
    bd.padOff[l] = padOff[l];
  }
  hipLaunchKernelGGL(build_all, dim3((258 * P[0] + 255) / 256, 5), dim3(256), 0,
                     stream, bd, bufA);

  ConvDesc cd;
  HeadDesc hd;
  CHDesc chd;
  SmallDesc nd;
  for (int i = 0; i <= 5; i++) {
    cd.tS[i] = tS128[i];
    hd.tS64[i] = tS64[i];
    chd.tS64[i] = tS64[i];
  }
  for (int l = 0; l < 5; l++) {
    cd.padOff[l] = padOff[l];
    cd.g[l] = GR[l];
    cd.P[l] = P[l];
    hd.padOff[l] = padOff[l];
    hd.g[l] = GR[l];
    hd.outOff[l] = smpl_off[l];
    chd.padOff[l] = padOff[l];
    chd.g[l] = GR[l];
    chd.outOff[l] = cumP[l];
    nd.P[l] = P[l];
    nd.g[l] = GR[l];
    nd.inOff[l] = cumP[l];
    nd.outOff[l] = cate_off[l];
  }

  const int NT64 = tS64[5];   // 242
  const int CGRID = 8 * 128;  // 1024 blocks: 8 xcd x (16 tiles x 4 coT x 2 towers)
  // merged tower conv stages
  hipLaunchKernelGGL(conv_mfma, dim3(CGRID), dim3(256), 0, stream, bufA, bufA, wHi,
                     wLo, pd.dstOff[0], pd.dstOff[4], smpl_b0, cate_b0, bufBs, bufBc,
                     cd, 9, 8);
  hipLaunchKernelGGL(conv_mfma, dim3(CGRID), dim3(256), 0, stream, bufBs, bufBc, wHi,
                     wLo, pd.dstOff[1], pd.dstOff[5], smpl_b + 0, cate_b + 0, bufCs,
                     bufCc, cd, 8, 8);
  hipLaunchKernelGGL(conv_mfma, dim3(CGRID), dim3(256), 0, stream, bufCs, bufCc, wHi,
                     wLo, pd.dstOff[2], pd.dstOff[6], smpl_b + 256, cate_b + 256,
                     bufBs, bufBc, cd, 8, 8);
  hipLaunchKernelGGL(conv_mfma, dim3(CGRID), dim3(256), 0, stream, bufBs, bufBc, wHi,
                     wLo, pd.dstOff[3], pd.dstOff[7], smpl_b + 512, cate_b + 512,
                     bufCs, bufCc, cd, 8, 8);
  // heads
  hipLaunchKernelGGL(head1x1, dim3(NT64, 3), dim3(256), 0, stream, bufCs,
                     wHi + pd.dstOff[8], wLo + pd.dstOff[8], smpl_head_b, smpl_init,
                     out, hd);
  hipLaunchKernelGGL(cate_head_all, dim3(NT64), dim3(256), 0, stream, bufCc,
                     cate_head_w, cate_head_b, heat, chd);
  hipLaunchKernelGGL(nms_all, dim3((P[0] + 255) / 256, 5), dim3(256), 0, stream, heat,
                     out, nd);
  (void)in_sizes;
  (void)n_in;
  (void)out_size;
  (void)ws_size;
}